// Round 3
// baseline (195.255 us; speedup 1.0000x reference)
//
#include <hip/hip_runtime.h>
#include <hip/hip_bf16.h>
#include <hip/hip_cooperative_groups.h>
#include <math.h>

namespace cg = cooperative_groups;

// ---------------------------------------------------------------------------
// Single cooperative kernel, 256 blocks x 256 threads (1 block/CU).
// P1: bf16 conv (Db=|bdw-gdw|, Wb=daw, x0b=x[:,0,:]) + partial minmax + misc
// P2: exact-f32 10-bin histograms of bdw,gdw,bow,gow
// P3: pu0 = unite(...) via bf16 MFMA 64x64-tile GEMM (256 tiles)
// P4: h partials = x0b @ pu0^T (split-K, 128 blocks)  ||  pu1 (16 blocks)
// P5: h=tanh(sum+b); out = h @ pu1^T + bob  (64 blocks)
// grid.sync() between phases; entropy path stays bit-exact f32.
//
// ws layout: words[8..11] bow/gow minmax, words[16..55] hist u32,
// words[64..1087] partial minmax; byte 8192: Db(2MB) Wb(2MB) x0b(128KB)
// pu0b(2MB) part(2MB f32) pu1(12KB).
// ---------------------------------------------------------------------------

#define NBINS 10

typedef short bf8v __attribute__((ext_vector_type(8)));
typedef float f32x4 __attribute__((ext_vector_type(4)));

static __device__ __forceinline__ unsigned short f2bf(float f) {
    __hip_bfloat16 h = __float2bfloat16(f);
    return __builtin_bit_cast(unsigned short, h);
}

#define GL2LDS(gp, lp) __builtin_amdgcn_global_load_lds(                       \
    (__attribute__((address_space(1))) void*)(gp),                             \
    (__attribute__((address_space(3))) void*)(lp), 16, 0, 0)

static __device__ __forceinline__ void stage_tile(const unsigned short* __restrict__ src,
                                                  short* lds_tile, int t, int row0, int k0) {
    int r = t >> 2, s = t & 3;
    int kg = s ^ ((r >> 1) & 3);
    GL2LDS(src + (size_t)(row0 + r) * 1024 + k0 + kg * 8, lds_tile + t * 8);
}

static __device__ __forceinline__ int frag_off(int row, int k8) {
    return row * 4 + (k8 ^ ((row >> 1) & 3));  // 16B units
}

static __device__ __forceinline__ void gemm_tiles(
    const unsigned short* __restrict__ Asrc, const unsigned short* __restrict__ Bsrc,
    int arow0, int brow0, int kbase, int nt, short* S, int t, f32x4 acc[2][2]) {
    short* As[2] = {S, S + 2048};
    short* Bs[2] = {S + 4096, S + 6144};
    const int lane = t & 63;
    const int wr = (t >> 6) >> 1, wc = (t >> 6) & 1;
    const int lr = lane & 15, k8 = lane >> 4;
    stage_tile(Asrc, As[0], t, arow0, kbase);
    stage_tile(Bsrc, Bs[0], t, brow0, kbase);
    int cur = 0;
    for (int tt = 0; tt < nt; ++tt) {
        __syncthreads();
        if (tt + 1 < nt) {
            stage_tile(Asrc, As[cur ^ 1], t, arow0, kbase + (tt + 1) * 32);
            stage_tile(Bsrc, Bs[cur ^ 1], t, brow0, kbase + (tt + 1) * 32);
        }
        const bf8v* Av = (const bf8v*)As[cur];
        const bf8v* Bv = (const bf8v*)Bs[cur];
        bf8v a0 = Av[frag_off(wr * 32 + lr, k8)];
        bf8v a1 = Av[frag_off(wr * 32 + 16 + lr, k8)];
        bf8v b0 = Bv[frag_off(wc * 32 + lr, k8)];
        bf8v b1 = Bv[frag_off(wc * 32 + 16 + lr, k8)];
        acc[0][0] = __builtin_amdgcn_mfma_f32_16x16x32_bf16(a0, b0, acc[0][0], 0, 0, 0);
        acc[0][1] = __builtin_amdgcn_mfma_f32_16x16x32_bf16(a0, b1, acc[0][1], 0, 0, 0);
        acc[1][0] = __builtin_amdgcn_mfma_f32_16x16x32_bf16(a1, b0, acc[1][0], 0, 0, 0);
        acc[1][1] = __builtin_amdgcn_mfma_f32_16x16x32_bf16(a1, b1, acc[1][1], 0, 0, 0);
        cur ^= 1;
    }
    __syncthreads();
}

static __device__ __forceinline__ float entropy_bins(unsigned* hist, float N) {
    float s = 0.0f;
    for (int b = 0; b < NBINS; b++) {
        unsigned c = atomicAdd(&hist[b], 0u);  // device-scope coherent read
        float p = __fdiv_rn((float)c, N);
        if (p > 0.0f) s += p * logf(p);
    }
    return -s;
}

__global__ __launch_bounds__(256) void k_mega(
    const float* __restrict__ x, const float* __restrict__ bdw, const float* __restrict__ bdb,
    const float* __restrict__ bow, const float* __restrict__ bob, const float* __restrict__ gdw,
    const float* __restrict__ gow, const float* __restrict__ daw, const float* __restrict__ dab,
    const float* __restrict__ oaw, const float* __restrict__ oab,
    float* __restrict__ out, char* __restrict__ ws) {
    cg::grid_group grid = cg::this_grid();
    const int blk = blockIdx.x, t = threadIdx.x;
    const int lane = t & 63, wid = t >> 6;

    float* ws_f = (float*)ws;
    unsigned* ws_u = (unsigned*)ws;
    unsigned short* Db   = (unsigned short*)(ws + 8192);
    unsigned short* Wb   = Db + 1048576;
    unsigned short* x0b  = Wb + 1048576;
    unsigned short* pu0b = x0b + 65536;
    float* part = (float*)(pu0b + 1048576);
    float* pu1  = part + 524288;

    __shared__ alignas(16) char smem[16384];
    __shared__ float s_small[32];
    __shared__ unsigned s_hist[NBINS];
    __shared__ float s_wgx;

    // ===== Phase 1: conv + partial minmax + x0b + bow/gow minmax + hist zero
    {
        float lo0 = INFINITY, hi0 = -INFINITY, lo1 = INFINITY, hi1 = -INFINITY;
        int base = blk * 1024;
#pragma unroll
        for (int q = 0; q < 4; q++) {
            int idx = base + q * 256 + t;
            float4 a = ((const float4*)bdw)[idx];
            float4 b = ((const float4*)gdw)[idx];
            float4 w = ((const float4*)daw)[idx];
            lo0 = fminf(lo0, fminf(fminf(a.x, a.y), fminf(a.z, a.w)));
            hi0 = fmaxf(hi0, fmaxf(fmaxf(a.x, a.y), fmaxf(a.z, a.w)));
            lo1 = fminf(lo1, fminf(fminf(b.x, b.y), fminf(b.z, b.w)));
            hi1 = fmaxf(hi1, fmaxf(fmaxf(b.x, b.y), fmaxf(b.z, b.w)));
            ushort4 d, ww;
            d.x = f2bf(fabsf(a.x - b.x)); d.y = f2bf(fabsf(a.y - b.y));
            d.z = f2bf(fabsf(a.z - b.z)); d.w = f2bf(fabsf(a.w - b.w));
            ww.x = f2bf(w.x); ww.y = f2bf(w.y); ww.z = f2bf(w.z); ww.w = f2bf(w.w);
            ((ushort4*)Db)[idx] = d;
            ((ushort4*)Wb)[idx] = ww;
        }
        for (int off = 32; off; off >>= 1) {
            lo0 = fminf(lo0, __shfl_down(lo0, off));
            hi0 = fmaxf(hi0, __shfl_down(hi0, off));
            lo1 = fminf(lo1, __shfl_down(lo1, off));
            hi1 = fmaxf(hi1, __shfl_down(hi1, off));
        }
        if (lane == 0) { s_small[wid] = lo0; s_small[4 + wid] = hi0; s_small[8 + wid] = lo1; s_small[12 + wid] = hi1; }
        __syncthreads();
        if (t == 0) {
            ws_f[64 + blk]       = fminf(fminf(s_small[0], s_small[1]), fminf(s_small[2], s_small[3]));
            ws_f[64 + 256 + blk] = fmaxf(fmaxf(s_small[4], s_small[5]), fmaxf(s_small[6], s_small[7]));
            ws_f[64 + 512 + blk] = fminf(fminf(s_small[8], s_small[9]), fminf(s_small[10], s_small[11]));
            ws_f[64 + 768 + blk] = fmaxf(fmaxf(s_small[12], s_small[13]), fmaxf(s_small[14], s_small[15]));
        }
        if (blk < 64) {
            float4 v = *(const float4*)&x[(size_t)blk * 524288 + t * 4];
            ushort4 o; o.x = f2bf(v.x); o.y = f2bf(v.y); o.z = f2bf(v.z); o.w = f2bf(v.w);
            ((ushort4*)x0b)[blk * 256 + t] = o;
        }
        if (blk == 64 || blk == 65) {
            const float* p = (blk == 64) ? bow : gow;
            float lo = INFINITY, hi = -INFINITY;
            for (int i = t; i < 3072; i += 256) { float v = p[i]; lo = fminf(lo, v); hi = fmaxf(hi, v); }
            for (int off = 32; off; off >>= 1) { lo = fminf(lo, __shfl_down(lo, off)); hi = fmaxf(hi, __shfl_down(hi, off)); }
            __syncthreads();  // retire P1 reads of s_small before reuse
            if (lane == 0) { s_small[wid] = lo; s_small[4 + wid] = hi; }
            __syncthreads();
            if (t == 0) {
                ws_f[8 + 2 * (blk - 64)] = fminf(fminf(s_small[0], s_small[1]), fminf(s_small[2], s_small[3]));
                ws_f[9 + 2 * (blk - 64)] = fmaxf(fmaxf(s_small[4], s_small[5]), fmaxf(s_small[6], s_small[7]));
            }
        }
        if (blk == 66 && t < 40) atomicExch(&ws_u[16 + t], 0u);
    }
    grid.sync();

    // ===== Phase 2: histograms (exact f32 bin arithmetic)
    {
        int m, b0, nb;
        if (blk < 120)      { m = 0; b0 = blk;       nb = 120; }
        else if (blk < 240) { m = 1; b0 = blk - 120; nb = 120; }
        else if (blk < 248) { m = 2; b0 = blk - 240; nb = 8; }
        else                { m = 3; b0 = blk - 248; nb = 8; }
        const float* p = (m == 0) ? bdw : (m == 1) ? gdw : (m == 2) ? bow : gow;
        int n = (m < 2) ? 1048576 : 3072;
        float lo, hi;
        if (m < 2) {
            float l = ws_f[64 + m * 512 + t];
            float h = ws_f[64 + m * 512 + 256 + t];
            for (int off = 32; off; off >>= 1) { l = fminf(l, __shfl_down(l, off)); h = fmaxf(h, __shfl_down(h, off)); }
            if (lane == 0) { s_small[wid] = l; s_small[4 + wid] = h; }
            __syncthreads();
            lo = fminf(fminf(s_small[0], s_small[1]), fminf(s_small[2], s_small[3]));
            hi = fmaxf(fmaxf(s_small[4], s_small[5]), fmaxf(s_small[6], s_small[7]));
        } else {
            lo = ws_f[8 + 2 * (m - 2)];
            hi = ws_f[9 + 2 * (m - 2)];
        }
        float scale = __fdiv_rn(__fsub_rn(hi, lo), 10.0f);
        float lower[NBINS], upper[NBINS];
#pragma unroll
        for (int b = 0; b < NBINS; b++) {
            lower[b] = __fadd_rn(lo, __fmul_rn((float)b, scale));
            upper[b] = __fadd_rn(lower[b], scale);
        }
        unsigned cnt[NBINS] = {};
        for (int i = b0 * 256 + t; i < n; i += nb * 256) {
            float v = p[i];
#pragma unroll
            for (int b = 0; b < NBINS; b++)
                if (v >= lower[b] && v < upper[b]) cnt[b]++;
        }
        if (t < NBINS) s_hist[t] = 0;
        __syncthreads();
#pragma unroll
        for (int b = 0; b < NBINS; b++)
            if (cnt[b]) atomicAdd(&s_hist[b], cnt[b]);
        __syncthreads();
        if (t < NBINS && s_hist[t]) atomicAdd(&ws_u[16 + m * NBINS + t], s_hist[t]);
    }
    grid.sync();

    // ===== Phase 3: pu0 GEMM (all 256 blocks, one 64x64 tile each)
    {
        if (t == 0) {
            float e0 = entropy_bins(&ws_u[16], 1048576.0f);
            float e1 = entropy_bins(&ws_u[26], 1048576.0f);
            s_wgx = (float)(0.4 / M_PI) * atanf(500.0f * (e0 - e1)) + 0.5f;
        }
        const int bi = blk >> 4, bj = blk & 15;
        f32x4 acc[2][2] = {};
        gemm_tiles(Db, Wb, bi * 64, bj * 64, 0, 32, (short*)smem, t, acc);
        float wg = s_wgx;
        const int wr = wid >> 1, wc = wid & 1;
        const int lr = lane & 15, k8 = lane >> 4;
#pragma unroll
        for (int mi = 0; mi < 2; mi++)
#pragma unroll
            for (int mj = 0; mj < 2; mj++)
#pragma unroll
                for (int r = 0; r < 4; r++) {
                    int i = bi * 64 + wr * 32 + mi * 16 + k8 * 4 + r;
                    int j = bj * 64 + wc * 32 + mj * 16 + lr;
                    float s = acc[mi][mj][r] + dab[j];
                    float wl = 1.0f / (1.0f + expf(-s));
                    float ww = wg * wl + (1.0f - wg);
                    float o = bdw[i * 1024 + j] * ww + gdw[i * 1024 + j] * (1.0f - ww);
                    pu0b[i * 1024 + j] = f2bf(o);
                }
    }
    grid.sync();

    // ===== Phase 4: h split-K GEMM (blocks 0..127) || pu1 (blocks 128..143)
    if (blk < 128) {
        const int bj = blk & 15, ks = blk >> 4;
        f32x4 acc[2][2] = {};
        gemm_tiles(x0b, pu0b, 0, bj * 64, ks * 128, 4, (short*)smem, t, acc);
        const int wr = wid >> 1, wc = wid & 1;
        const int lr = lane & 15, k8 = lane >> 4;
#pragma unroll
        for (int mi = 0; mi < 2; mi++)
#pragma unroll
            for (int mj = 0; mj < 2; mj++)
#pragma unroll
                for (int r = 0; r < 4; r++) {
                    int mrow = wr * 32 + mi * 16 + k8 * 4 + r;
                    int c = bj * 64 + wc * 32 + mj * 16 + lr;
                    part[(size_t)(ks * 64 + mrow) * 1024 + c] = acc[mi][mj][r];
                }
    } else if (blk < 144) {
        if (t == 0) {
            float e2 = entropy_bins(&ws_u[36], 3072.0f);
            float e3 = entropy_bins(&ws_u[46], 3072.0f);
            s_wgx = (float)(0.4 / M_PI) * atanf(500.0f * (e2 - e3)) + 0.5f;
        }
        float* D = (float*)smem;          // 3x1024
        float* P = (float*)smem + 3072;   // 3x4x64
        for (int idx = t; idx < 3072; idx += 256)
            D[idx] = fabsf(bow[idx] - gow[idx]);
        __syncthreads();
        int bj = blk - 128;
        int c = bj * 64 + (t & 63);
        int kp = t >> 6;
        float a0 = 0.f, a1 = 0.f, a2 = 0.f;
        for (int k = kp * 256; k < kp * 256 + 256; k += 4) {
            float4 wv = *(const float4*)&oaw[c * 1024 + k];
            float4 d0 = *(const float4*)&D[k];
            float4 d1 = *(const float4*)&D[1024 + k];
            float4 d2 = *(const float4*)&D[2048 + k];
            a0 += d0.x * wv.x + d0.y * wv.y + d0.z * wv.z + d0.w * wv.w;
            a1 += d1.x * wv.x + d1.y * wv.y + d1.z * wv.z + d1.w * wv.w;
            a2 += d2.x * wv.x + d2.y * wv.y + d2.z * wv.z + d2.w * wv.w;
        }
        P[0 * 256 + kp * 64 + (t & 63)] = a0;
        P[1 * 256 + kp * 64 + (t & 63)] = a1;
        P[2 * 256 + kp * 64 + (t & 63)] = a2;
        __syncthreads();
        if (t < 192) {
            int r = t >> 6, cc = t & 63;
            int c2 = bj * 64 + cc;
            float s = P[r * 256 + cc] + P[r * 256 + 64 + cc] + P[r * 256 + 128 + cc] + P[r * 256 + 192 + cc] + oab[c2];
            float wl = 1.0f / (1.0f + expf(-s));
            float wg = s_wgx;
            float w = wg * wl + (1.0f - wg);
            pu1[r * 1024 + c2] = bow[r * 1024 + c2] * w + gow[r * 1024 + c2] * (1.0f - w);
        }
    }
    grid.sync();

    // ===== Phase 5: h = tanh(sum + bdb); out = h @ pu1^T + bob (blocks 0..63)
    if (blk < 64) {
        float* hrow = (float*)smem;          // 1024
        float* pc   = (float*)smem + 1024;   // 3x1024
#pragma unroll
        for (int q = 0; q < 4; q++) {
            int c = q * 256 + t;
            float s = 0.0f;
#pragma unroll
            for (int ks = 0; ks < 8; ks++) s += part[(size_t)(ks * 64 + blk) * 1024 + c];
            hrow[c] = tanhf(s + bdb[c]);
        }
        for (int i = t; i < 3072; i += 256) pc[i] = pu1[i];
        __syncthreads();
        float p0 = 0.f, p1 = 0.f, p2 = 0.f;
#pragma unroll
        for (int q = 0; q < 4; q++) {
            int c = q * 256 + t;
            float hv = hrow[c];
            p0 += hv * pc[c];
            p1 += hv * pc[1024 + c];
            p2 += hv * pc[2048 + c];
        }
        for (int off = 32; off; off >>= 1) {
            p0 += __shfl_down(p0, off);
            p1 += __shfl_down(p1, off);
            p2 += __shfl_down(p2, off);
        }
        if (lane == 0) { s_small[wid] = p0; s_small[4 + wid] = p1; s_small[8 + wid] = p2; }
        __syncthreads();
        if (t == 0) {
            out[blk * 3 + 0] = s_small[0] + s_small[1] + s_small[2] + s_small[3] + bob[0];
            out[blk * 3 + 1] = s_small[4] + s_small[5] + s_small[6] + s_small[7] + bob[1];
            out[blk * 3 + 2] = s_small[8] + s_small[9] + s_small[10] + s_small[11] + bob[2];
        }
    }
}

extern "C" void kernel_launch(void* const* d_in, const int* in_sizes, int n_in,
                              void* d_out, int out_size, void* d_ws, size_t ws_size,
                              hipStream_t stream) {
    const float* x   = (const float*)d_in[0];
    const float* bdw = (const float*)d_in[1];
    const float* bdb = (const float*)d_in[2];
    const float* bow = (const float*)d_in[3];
    const float* bob = (const float*)d_in[4];
    const float* gdw = (const float*)d_in[5];
    const float* gow = (const float*)d_in[6];
    const float* daw = (const float*)d_in[7];
    const float* dab = (const float*)d_in[8];
    const float* oaw = (const float*)d_in[9];
    const float* oab = (const float*)d_in[10];
    float* out = (float*)d_out;
    char* ws = (char*)d_ws;

    void* args[] = {&x, &bdw, &bdb, &bow, &bob, &gdw, &gow, &daw, &dab, &oaw, &oab, &out, &ws};
    hipLaunchCooperativeKernel((const void*)k_mega, dim3(256), dim3(256), args, 0, stream);
}

// Round 4
// 173.423 us; speedup vs baseline: 1.1259x; 1.1259x over previous
//
#include <hip/hip_runtime.h>
#include <hip/hip_bf16.h>
#include <math.h>

// ---------------------------------------------------------------------------
// Single cooperative kernel, 256 blocks x 256 threads (1 block/CU), with a
// CUSTOM fast grid barrier (cg::grid.sync()'s s_sleep backoff cost ~40us/sync
// in round 3; this is ~1.5us/sync: fire-and-forget atomicAdd arrival + relaxed
// agent-scope polling + threadfence release/acquire).
// Phases:
// P1: bf16 conv (Db=|bdw-gdw|, Wb=daw, x0b=x[:,0,:]) + partial minmax
// P2: exact-f32 10-bin histograms of bdw,gdw,bow,gow
// P3: pu0 = unite(...) via bf16 MFMA 64x64-tile GEMM (256 tiles)
// P4: h partials = x0b @ pu0^T (split-K, 128 blocks)  ||  pu1 (16 blocks)
// P5: h=tanh(sum+b); out = h @ pu1^T + bob  (64 blocks)
// Entropy path stays bit-exact f32 (500x amplified by atan).
//
// ws: word0 = barrier counter (zeroed by hipMemsetAsync each call);
// words[8..11] bow/gow minmax; words[16..55] hist u32 (zeroed by memset);
// words[64..1087] partial minmax; byte 8192: Db(2MB) Wb(2MB) x0b(128KB)
// pu0b(2MB) part(2MB f32) pu1(12KB).
// ---------------------------------------------------------------------------

#define NBINS 10

typedef short bf8v __attribute__((ext_vector_type(8)));
typedef float f32x4 __attribute__((ext_vector_type(4)));

static __device__ __forceinline__ unsigned short f2bf(float f) {
    __hip_bfloat16 h = __float2bfloat16(f);
    return __builtin_bit_cast(unsigned short, h);
}

#define GL2LDS(gp, lp) __builtin_amdgcn_global_load_lds(                       \
    (__attribute__((address_space(1))) void*)(gp),                             \
    (__attribute__((address_space(3))) void*)(lp), 16, 0, 0)

// Fast grid barrier: all blocks arrive (atomicAdd), t0 polls until counter
// reaches `target`, device fences give release/acquire semantics.
static __device__ __forceinline__ void gbar(unsigned* cnt, unsigned target) {
    __syncthreads();
    if (threadIdx.x == 0) {
        __threadfence();  // release: make this block's writes visible
        __hip_atomic_fetch_add(cnt, 1u, __ATOMIC_RELAXED, __HIP_MEMORY_SCOPE_AGENT);
        while (__hip_atomic_load(cnt, __ATOMIC_RELAXED, __HIP_MEMORY_SCOPE_AGENT) < target)
            __builtin_amdgcn_s_sleep(2);
        __threadfence();  // acquire: invalidate stale cache, see others' writes
    }
    __syncthreads();
}

static __device__ __forceinline__ void stage_tile(const unsigned short* __restrict__ src,
                                                  short* lds_tile, int t, int row0, int k0) {
    int r = t >> 2, s = t & 3;
    int kg = s ^ ((r >> 1) & 3);
    GL2LDS(src + (size_t)(row0 + r) * 1024 + k0 + kg * 8, lds_tile + t * 8);
}

static __device__ __forceinline__ int frag_off(int row, int k8) {
    return row * 4 + (k8 ^ ((row >> 1) & 3));  // 16B units
}

static __device__ __forceinline__ void gemm_tiles(
    const unsigned short* __restrict__ Asrc, const unsigned short* __restrict__ Bsrc,
    int arow0, int brow0, int kbase, int nt, short* S, int t, f32x4 acc[2][2]) {
    short* As[2] = {S, S + 2048};
    short* Bs[2] = {S + 4096, S + 6144};
    const int lane = t & 63;
    const int wr = (t >> 6) >> 1, wc = (t >> 6) & 1;
    const int lr = lane & 15, k8 = lane >> 4;
    stage_tile(Asrc, As[0], t, arow0, kbase);
    stage_tile(Bsrc, Bs[0], t, brow0, kbase);
    int cur = 0;
    for (int tt = 0; tt < nt; ++tt) {
        __syncthreads();
        if (tt + 1 < nt) {
            stage_tile(Asrc, As[cur ^ 1], t, arow0, kbase + (tt + 1) * 32);
            stage_tile(Bsrc, Bs[cur ^ 1], t, brow0, kbase + (tt + 1) * 32);
        }
        const bf8v* Av = (const bf8v*)As[cur];
        const bf8v* Bv = (const bf8v*)Bs[cur];
        bf8v a0 = Av[frag_off(wr * 32 + lr, k8)];
        bf8v a1 = Av[frag_off(wr * 32 + 16 + lr, k8)];
        bf8v b0 = Bv[frag_off(wc * 32 + lr, k8)];
        bf8v b1 = Bv[frag_off(wc * 32 + 16 + lr, k8)];
        acc[0][0] = __builtin_amdgcn_mfma_f32_16x16x32_bf16(a0, b0, acc[0][0], 0, 0, 0);
        acc[0][1] = __builtin_amdgcn_mfma_f32_16x16x32_bf16(a0, b1, acc[0][1], 0, 0, 0);
        acc[1][0] = __builtin_amdgcn_mfma_f32_16x16x32_bf16(a1, b0, acc[1][0], 0, 0, 0);
        acc[1][1] = __builtin_amdgcn_mfma_f32_16x16x32_bf16(a1, b1, acc[1][1], 0, 0, 0);
        cur ^= 1;
    }
    __syncthreads();
}

static __device__ __forceinline__ float entropy_bins(const unsigned* hist, float N) {
    float s = 0.0f;
    for (int b = 0; b < NBINS; b++) {
        float p = __fdiv_rn((float)hist[b], N);
        if (p > 0.0f) s += p * logf(p);
    }
    return -s;
}

__global__ __launch_bounds__(256) void k_mega(
    const float* __restrict__ x, const float* __restrict__ bdw, const float* __restrict__ bdb,
    const float* __restrict__ bow, const float* __restrict__ bob, const float* __restrict__ gdw,
    const float* __restrict__ gow, const float* __restrict__ daw, const float* __restrict__ dab,
    const float* __restrict__ oaw, const float* __restrict__ oab,
    float* __restrict__ out, char* __restrict__ ws) {
    const int blk = blockIdx.x, t = threadIdx.x;
    const int lane = t & 63, wid = t >> 6;

    float* ws_f = (float*)ws;
    unsigned* ws_u = (unsigned*)ws;
    unsigned* bar = ws_u;  // word 0, memset to 0 before each launch
    unsigned short* Db   = (unsigned short*)(ws + 8192);
    unsigned short* Wb   = Db + 1048576;
    unsigned short* x0b  = Wb + 1048576;
    unsigned short* pu0b = x0b + 65536;
    float* part = (float*)(pu0b + 1048576);
    float* pu1  = part + 524288;

    __shared__ alignas(16) char smem[16384];
    __shared__ float s_small[32];
    __shared__ unsigned s_hist[NBINS];
    __shared__ float s_wgx;

    // ===== Phase 1: conv + partial minmax + x0b + bow/gow minmax
    {
        float lo0 = INFINITY, hi0 = -INFINITY, lo1 = INFINITY, hi1 = -INFINITY;
        int base = blk * 1024;
#pragma unroll
        for (int q = 0; q < 4; q++) {
            int idx = base + q * 256 + t;
            float4 a = ((const float4*)bdw)[idx];
            float4 b = ((const float4*)gdw)[idx];
            float4 w = ((const float4*)daw)[idx];
            lo0 = fminf(lo0, fminf(fminf(a.x, a.y), fminf(a.z, a.w)));
            hi0 = fmaxf(hi0, fmaxf(fmaxf(a.x, a.y), fmaxf(a.z, a.w)));
            lo1 = fminf(lo1, fminf(fminf(b.x, b.y), fminf(b.z, b.w)));
            hi1 = fmaxf(hi1, fmaxf(fmaxf(b.x, b.y), fmaxf(b.z, b.w)));
            ushort4 d, ww;
            d.x = f2bf(fabsf(a.x - b.x)); d.y = f2bf(fabsf(a.y - b.y));
            d.z = f2bf(fabsf(a.z - b.z)); d.w = f2bf(fabsf(a.w - b.w));
            ww.x = f2bf(w.x); ww.y = f2bf(w.y); ww.z = f2bf(w.z); ww.w = f2bf(w.w);
            ((ushort4*)Db)[idx] = d;
            ((ushort4*)Wb)[idx] = ww;
        }
        for (int off = 32; off; off >>= 1) {
            lo0 = fminf(lo0, __shfl_down(lo0, off));
            hi0 = fmaxf(hi0, __shfl_down(hi0, off));
            lo1 = fminf(lo1, __shfl_down(lo1, off));
            hi1 = fmaxf(hi1, __shfl_down(hi1, off));
        }
        if (lane == 0) { s_small[wid] = lo0; s_small[4 + wid] = hi0; s_small[8 + wid] = lo1; s_small[12 + wid] = hi1; }
        __syncthreads();
        if (t == 0) {
            ws_f[64 + blk]       = fminf(fminf(s_small[0], s_small[1]), fminf(s_small[2], s_small[3]));
            ws_f[64 + 256 + blk] = fmaxf(fmaxf(s_small[4], s_small[5]), fmaxf(s_small[6], s_small[7]));
            ws_f[64 + 512 + blk] = fminf(fminf(s_small[8], s_small[9]), fminf(s_small[10], s_small[11]));
            ws_f[64 + 768 + blk] = fmaxf(fmaxf(s_small[12], s_small[13]), fmaxf(s_small[14], s_small[15]));
        }
        if (blk < 64) {
            float4 v = *(const float4*)&x[(size_t)blk * 524288 + t * 4];
            ushort4 o; o.x = f2bf(v.x); o.y = f2bf(v.y); o.z = f2bf(v.z); o.w = f2bf(v.w);
            ((ushort4*)x0b)[blk * 256 + t] = o;
        }
        if (blk == 64 || blk == 65) {
            const float* p = (blk == 64) ? bow : gow;
            float lo = INFINITY, hi = -INFINITY;
            for (int i = t; i < 3072; i += 256) { float v = p[i]; lo = fminf(lo, v); hi = fmaxf(hi, v); }
            for (int off = 32; off; off >>= 1) { lo = fminf(lo, __shfl_down(lo, off)); hi = fmaxf(hi, __shfl_down(hi, off)); }
            __syncthreads();  // retire P1 reads of s_small before reuse
            if (lane == 0) { s_small[wid] = lo; s_small[4 + wid] = hi; }
            __syncthreads();
            if (t == 0) {
                ws_f[8 + 2 * (blk - 64)] = fminf(fminf(s_small[0], s_small[1]), fminf(s_small[2], s_small[3]));
                ws_f[9 + 2 * (blk - 64)] = fmaxf(fmaxf(s_small[4], s_small[5]), fmaxf(s_small[6], s_small[7]));
            }
        }
    }
    gbar(bar, 256);

    // ===== Phase 2: histograms (exact f32 bin arithmetic; bins pre-zeroed by memset)
    {
        int m, b0, nb;
        if (blk < 120)      { m = 0; b0 = blk;       nb = 120; }
        else if (blk < 240) { m = 1; b0 = blk - 120; nb = 120; }
        else if (blk < 248) { m = 2; b0 = blk - 240; nb = 8; }
        else                { m = 3; b0 = blk - 248; nb = 8; }
        const float* p = (m == 0) ? bdw : (m == 1) ? gdw : (m == 2) ? bow : gow;
        int n = (m < 2) ? 1048576 : 3072;
        float lo, hi;
        if (m < 2) {
            float l = ws_f[64 + m * 512 + t];
            float h = ws_f[64 + m * 512 + 256 + t];
            for (int off = 32; off; off >>= 1) { l = fminf(l, __shfl_down(l, off)); h = fmaxf(h, __shfl_down(h, off)); }
            if (lane == 0) { s_small[wid] = l; s_small[4 + wid] = h; }
            __syncthreads();
            lo = fminf(fminf(s_small[0], s_small[1]), fminf(s_small[2], s_small[3]));
            hi = fmaxf(fmaxf(s_small[4], s_small[5]), fmaxf(s_small[6], s_small[7]));
        } else {
            lo = ws_f[8 + 2 * (m - 2)];
            hi = ws_f[9 + 2 * (m - 2)];
        }
        float scale = __fdiv_rn(__fsub_rn(hi, lo), 10.0f);
        float lower[NBINS], upper[NBINS];
#pragma unroll
        for (int b = 0; b < NBINS; b++) {
            lower[b] = __fadd_rn(lo, __fmul_rn((float)b, scale));
            upper[b] = __fadd_rn(lower[b], scale);
        }
        unsigned cnt[NBINS] = {};
        for (int i = b0 * 256 + t; i < n; i += nb * 256) {
            float v = p[i];
#pragma unroll
            for (int b = 0; b < NBINS; b++)
                if (v >= lower[b] && v < upper[b]) cnt[b]++;
        }
        if (t < NBINS) s_hist[t] = 0;
        __syncthreads();
#pragma unroll
        for (int b = 0; b < NBINS; b++)
            if (cnt[b]) atomicAdd(&s_hist[b], cnt[b]);
        __syncthreads();
        if (t < NBINS && s_hist[t]) atomicAdd(&ws_u[16 + m * NBINS + t], s_hist[t]);
    }
    gbar(bar, 512);

    // ===== Phase 3: pu0 GEMM (all 256 blocks, one 64x64 tile each)
    {
        if (t == 0) {
            float e0 = entropy_bins(&ws_u[16], 1048576.0f);
            float e1 = entropy_bins(&ws_u[26], 1048576.0f);
            s_wgx = (float)(0.4 / M_PI) * atanf(500.0f * (e0 - e1)) + 0.5f;
        }
        const int bi = blk >> 4, bj = blk & 15;
        f32x4 acc[2][2] = {};
        gemm_tiles(Db, Wb, bi * 64, bj * 64, 0, 32, (short*)smem, t, acc);
        float wg = s_wgx;
        const int wr = wid >> 1, wc = wid & 1;
        const int lr = lane & 15, k8 = lane >> 4;
#pragma unroll
        for (int mi = 0; mi < 2; mi++)
#pragma unroll
            for (int mj = 0; mj < 2; mj++)
#pragma unroll
                for (int r = 0; r < 4; r++) {
                    int i = bi * 64 + wr * 32 + mi * 16 + k8 * 4 + r;
                    int j = bj * 64 + wc * 32 + mj * 16 + lr;
                    float s = acc[mi][mj][r] + dab[j];
                    float wl = 1.0f / (1.0f + expf(-s));
                    float ww = wg * wl + (1.0f - wg);
                    float o = bdw[i * 1024 + j] * ww + gdw[i * 1024 + j] * (1.0f - ww);
                    pu0b[i * 1024 + j] = f2bf(o);
                }
    }
    gbar(bar, 768);

    // ===== Phase 4: h split-K GEMM (blocks 0..127) || pu1 (blocks 128..143)
    if (blk < 128) {
        const int bj = blk & 15, ks = blk >> 4;
        f32x4 acc[2][2] = {};
        gemm_tiles(x0b, pu0b, 0, bj * 64, ks * 128, 4, (short*)smem, t, acc);
        const int wr = wid >> 1, wc = wid & 1;
        const int lr = lane & 15, k8 = lane >> 4;
#pragma unroll
        for (int mi = 0; mi < 2; mi++)
#pragma unroll
            for (int mj = 0; mj < 2; mj++)
#pragma unroll
                for (int r = 0; r < 4; r++) {
                    int mrow = wr * 32 + mi * 16 + k8 * 4 + r;
                    int c = bj * 64 + wc * 32 + mj * 16 + lr;
                    part[(size_t)(ks * 64 + mrow) * 1024 + c] = acc[mi][mj][r];
                }
    } else if (blk < 144) {
        if (t == 0) {
            float e2 = entropy_bins(&ws_u[36], 3072.0f);
            float e3 = entropy_bins(&ws_u[46], 3072.0f);
            s_wgx = (float)(0.4 / M_PI) * atanf(500.0f * (e2 - e3)) + 0.5f;
        }
        float* D = (float*)smem;          // 3x1024
        float* P = (float*)smem + 3072;   // 3x4x64
        for (int idx = t; idx < 3072; idx += 256)
            D[idx] = fabsf(bow[idx] - gow[idx]);
        __syncthreads();
        int bj = blk - 128;
        int c = bj * 64 + (t & 63);
        int kp = t >> 6;
        float a0 = 0.f, a1 = 0.f, a2 = 0.f;
        for (int k = kp * 256; k < kp * 256 + 256; k += 4) {
            float4 wv = *(const float4*)&oaw[c * 1024 + k];
            float4 d0 = *(const float4*)&D[k];
            float4 d1 = *(const float4*)&D[1024 + k];
            float4 d2 = *(const float4*)&D[2048 + k];
            a0 += d0.x * wv.x + d0.y * wv.y + d0.z * wv.z + d0.w * wv.w;
            a1 += d1.x * wv.x + d1.y * wv.y + d1.z * wv.z + d1.w * wv.w;
            a2 += d2.x * wv.x + d2.y * wv.y + d2.z * wv.z + d2.w * wv.w;
        }
        P[0 * 256 + kp * 64 + (t & 63)] = a0;
        P[1 * 256 + kp * 64 + (t & 63)] = a1;
        P[2 * 256 + kp * 64 + (t & 63)] = a2;
        __syncthreads();
        if (t < 192) {
            int r = t >> 6, cc = t & 63;
            int c2 = bj * 64 + cc;
            float s = P[r * 256 + cc] + P[r * 256 + 64 + cc] + P[r * 256 + 128 + cc] + P[r * 256 + 192 + cc] + oab[c2];
            float wl = 1.0f / (1.0f + expf(-s));
            float wg = s_wgx;
            float w = wg * wl + (1.0f - wg);
            pu1[r * 1024 + c2] = bow[r * 1024 + c2] * w + gow[r * 1024 + c2] * (1.0f - w);
        }
    }
    gbar(bar, 1024);

    // ===== Phase 5: h = tanh(sum + bdb); out = h @ pu1^T + bob (blocks 0..63)
    if (blk < 64) {
        float* hrow = (float*)smem;          // 1024
        float* pc   = (float*)smem + 1024;   // 3x1024
#pragma unroll
        for (int q = 0; q < 4; q++) {
            int c = q * 256 + t;
            float s = 0.0f;
#pragma unroll
            for (int ks = 0; ks < 8; ks++) s += part[(size_t)(ks * 64 + blk) * 1024 + c];
            hrow[c] = tanhf(s + bdb[c]);
        }
        for (int i = t; i < 3072; i += 256) pc[i] = pu1[i];
        __syncthreads();
        float p0 = 0.f, p1 = 0.f, p2 = 0.f;
#pragma unroll
        for (int q = 0; q < 4; q++) {
            int c = q * 256 + t;
            float hv = hrow[c];
            p0 += hv * pc[c];
            p1 += hv * pc[1024 + c];
            p2 += hv * pc[2048 + c];
        }
        for (int off = 32; off; off >>= 1) {
            p0 += __shfl_down(p0, off);
            p1 += __shfl_down(p1, off);
            p2 += __shfl_down(p2, off);
        }
        if (lane == 0) { s_small[wid] = p0; s_small[4 + wid] = p1; s_small[8 + wid] = p2; }
        __syncthreads();
        if (t == 0) {
            out[blk * 3 + 0] = s_small[0] + s_small[1] + s_small[2] + s_small[3] + bob[0];
            out[blk * 3 + 1] = s_small[4] + s_small[5] + s_small[6] + s_small[7] + bob[1];
            out[blk * 3 + 2] = s_small[8] + s_small[9] + s_small[10] + s_small[11] + bob[2];
        }
    }
}

extern "C" void kernel_launch(void* const* d_in, const int* in_sizes, int n_in,
                              void* d_out, int out_size, void* d_ws, size_t ws_size,
                              hipStream_t stream) {
    const float* x   = (const float*)d_in[0];
    const float* bdw = (const float*)d_in[1];
    const float* bdb = (const float*)d_in[2];
    const float* bow = (const float*)d_in[3];
    const float* bob = (const float*)d_in[4];
    const float* gdw = (const float*)d_in[5];
    const float* gow = (const float*)d_in[6];
    const float* daw = (const float*)d_in[7];
    const float* dab = (const float*)d_in[8];
    const float* oaw = (const float*)d_in[9];
    const float* oab = (const float*)d_in[10];
    float* out = (float*)d_out;
    char* ws = (char*)d_ws;

    // zero barrier counter + minmax slots + histogram bins (words 0..63)
    hipMemsetAsync(d_ws, 0, 256, stream);

    void* args[] = {&x, &bdw, &bdb, &bow, &bob, &gdw, &gow, &daw, &dab, &oaw, &oab, &out, &ws};
    hipLaunchCooperativeKernel((const void*)k_mega, dim3(256), dim3(256), args, 0, stream);
}

// Round 5
// 105.587 us; speedup vs baseline: 1.8492x; 1.6425x over previous
//
#include <hip/hip_runtime.h>
#include <hip/hip_bf16.h>
#include <math.h>

// ---------------------------------------------------------------------------
// Single cooperative kernel, 256 blocks x 256 threads, ZERO cache-maintenance
// fences. All cross-block data moves through relaxed agent-scope atomics
// (coherent per-address, no buffer_wbl2/buffer_inv L2 walks — round 4 showed
// __threadfence costs ~30us each here). Inputs are read-only => coherent.
//
// P-A: per-block minmax partials of bdw,gdw (+bow/gow) -> coherent slots
// P-B: S1 = |bow-gow|@oaw^T (blocks 0-63, overlapped) ; exact-f32 histograms
// P-C: pu0 GEMM 64x64 tile/block, f32->bf16 on the fly, bf16 MFMA; epilogue
//      combines with wg0 and FUSES the 64x64x64 h-contribution mini-GEMM
//      (pu0 tile transposed through LDS), storing f32 h-partials coherently.
//      Blocks 0-15 also combine pu1.
// P-D: blocks 0-63: h = tanh(sum part2 + bdb); out = h @ pu1^T + bob.
//
// Barriers: __syncthreads (drains vmcnt = release) + relaxed atomic arrive +
// relaxed spin on monotonic targets 256/512/768. Counter zeroed by a 256-byte
// hipMemsetAsync each call (also zeroes the histogram bins).
//
// ws layout (f32 words): [0]=barrier cnt; [8..11]=bow/gow minmax;
// u32[16..55]=bins; [64..1087]=minmax slots 4x256; [1088..4159]=S1 3x1024;
// [4224..7295]=pu1 3x1024; [8192..]=part2 f32 [16][64][1024] (4 MB).
// ---------------------------------------------------------------------------

#define NBINS 10
typedef short bf8v __attribute__((ext_vector_type(8)));
typedef float f32x4 __attribute__((ext_vector_type(4)));

#define AST(p, v) __hip_atomic_store((p), (v), __ATOMIC_RELAXED, __HIP_MEMORY_SCOPE_AGENT)
#define ALD(p)    __hip_atomic_load((p), __ATOMIC_RELAXED, __HIP_MEMORY_SCOPE_AGENT)

static __device__ __forceinline__ unsigned short f2bf(float f) {
    __hip_bfloat16 h = __float2bfloat16(f);
    return __builtin_bit_cast(unsigned short, h);
}
static __device__ __forceinline__ bf8v cvt8(float4 a, float4 b) {
    bf8v r;
    r[0] = (short)f2bf(a.x); r[1] = (short)f2bf(a.y); r[2] = (short)f2bf(a.z); r[3] = (short)f2bf(a.w);
    r[4] = (short)f2bf(b.x); r[5] = (short)f2bf(b.y); r[6] = (short)f2bf(b.z); r[7] = (short)f2bf(b.w);
    return r;
}
static __device__ __forceinline__ bf8v cvt8abs(float4 a0, float4 a1, float4 b0, float4 b1) {
    bf8v r;
    r[0] = (short)f2bf(fabsf(a0.x - b0.x)); r[1] = (short)f2bf(fabsf(a0.y - b0.y));
    r[2] = (short)f2bf(fabsf(a0.z - b0.z)); r[3] = (short)f2bf(fabsf(a0.w - b0.w));
    r[4] = (short)f2bf(fabsf(a1.x - b1.x)); r[5] = (short)f2bf(fabsf(a1.y - b1.y));
    r[6] = (short)f2bf(fabsf(a1.z - b1.z)); r[7] = (short)f2bf(fabsf(a1.w - b1.w));
    return r;
}

// __syncthreads drains each wave's vmcnt before s_barrier -> prior coherent
// stores are ACKed at the coherence point before t0's arrive is issued.
static __device__ __forceinline__ void bar_arrive(unsigned* cnt) {
    __syncthreads();
    if (threadIdx.x == 0)
        __hip_atomic_fetch_add(cnt, 1u, __ATOMIC_RELAXED, __HIP_MEMORY_SCOPE_AGENT);
}
static __device__ __forceinline__ void bar_wait(unsigned* cnt, unsigned target) {
    if (threadIdx.x == 0)
        while (__hip_atomic_load(cnt, __ATOMIC_RELAXED, __HIP_MEMORY_SCOPE_AGENT) < target)
            __builtin_amdgcn_s_sleep(1);
    __syncthreads();
}

static __device__ __forceinline__ int frag_off(int row, int k8) {
    return row * 4 + (k8 ^ ((row >> 1) & 3));  // 16B units, XOR-swizzled
}

static __device__ __forceinline__ float ent_bins(const unsigned* bins, float N) {
    float s = 0.0f;
    for (int b = 0; b < NBINS; b++) {
        float p = __fdiv_rn((float)ALD(&bins[b]), N);
        if (p > 0.0f) s += p * logf(p);
    }
    return -s;
}

__global__ __launch_bounds__(256) void k_mega(
    const float* __restrict__ x, const float* __restrict__ bdw, const float* __restrict__ bdb,
    const float* __restrict__ bow, const float* __restrict__ bob, const float* __restrict__ gdw,
    const float* __restrict__ gow, const float* __restrict__ daw, const float* __restrict__ dab,
    const float* __restrict__ oaw, const float* __restrict__ oab,
    float* __restrict__ out, char* __restrict__ ws) {
    const int blk = blockIdx.x, t = threadIdx.x;
    const int lane = t & 63, wid = t >> 6;
    const int lr = lane & 15, k8 = lane >> 4;
    const int wr = wid >> 1, wc = wid & 1;

    float* ws_f = (float*)ws;
    unsigned* ws_u = (unsigned*)ws;
    unsigned* cnt = ws_u;            // zeroed by memset each call
    unsigned* bins = ws_u + 16;      // 4x10, zeroed by memset each call
    float* slots = ws_f + 64;        // 4x256 partial minmax
    float* S1   = ws_f + 1088;       // 3x1024
    float* pu1  = ws_f + 4224;       // 3x1024
    float* part2 = ws_f + 8192;      // [16][64][1024]

    __shared__ short lds_a[2][2048];
    __shared__ short lds_b[2][2048];
    __shared__ short ldsT[64 * 72];
    __shared__ float sp[192];
    __shared__ float s_small[16];
    __shared__ unsigned s_hist[NBINS];
    __shared__ float s_wg[2];

    // ===== Phase A: minmax partials ==========================================
    {
        float lo0 = INFINITY, hi0 = -INFINITY, lo1 = INFINITY, hi1 = -INFINITY;
        int fbase = blk * 1024 + t;
#pragma unroll
        for (int q = 0; q < 4; q++) {
            float4 a = ((const float4*)bdw)[fbase + q * 256];
            float4 b = ((const float4*)gdw)[fbase + q * 256];
            lo0 = fminf(lo0, fminf(fminf(a.x, a.y), fminf(a.z, a.w)));
            hi0 = fmaxf(hi0, fmaxf(fmaxf(a.x, a.y), fmaxf(a.z, a.w)));
            lo1 = fminf(lo1, fminf(fminf(b.x, b.y), fminf(b.z, b.w)));
            hi1 = fmaxf(hi1, fmaxf(fmaxf(b.x, b.y), fmaxf(b.z, b.w)));
        }
        for (int off = 32; off; off >>= 1) {
            lo0 = fminf(lo0, __shfl_down(lo0, off));
            hi0 = fmaxf(hi0, __shfl_down(hi0, off));
            lo1 = fminf(lo1, __shfl_down(lo1, off));
            hi1 = fmaxf(hi1, __shfl_down(hi1, off));
        }
        if (lane == 0) { s_small[wid] = lo0; s_small[4 + wid] = hi0; s_small[8 + wid] = lo1; s_small[12 + wid] = hi1; }
        __syncthreads();
        if (t == 0) {
            AST(&slots[blk],       fminf(fminf(s_small[0], s_small[1]), fminf(s_small[2], s_small[3])));
            AST(&slots[256 + blk], fmaxf(fmaxf(s_small[4], s_small[5]), fmaxf(s_small[6], s_small[7])));
            AST(&slots[512 + blk], fminf(fminf(s_small[8], s_small[9]), fminf(s_small[10], s_small[11])));
            AST(&slots[768 + blk], fmaxf(fmaxf(s_small[12], s_small[13]), fmaxf(s_small[14], s_small[15])));
        }
        if (blk == 64 || blk == 65) {
            const float* p = (blk == 64) ? bow : gow;
            float lo = INFINITY, hi = -INFINITY;
#pragma unroll
            for (int q = 0; q < 12; q++) { float v = p[q * 256 + t]; lo = fminf(lo, v); hi = fmaxf(hi, v); }
            for (int off = 32; off; off >>= 1) { lo = fminf(lo, __shfl_down(lo, off)); hi = fmaxf(hi, __shfl_down(hi, off)); }
            __syncthreads();
            if (lane == 0) { s_small[wid] = lo; s_small[4 + wid] = hi; }
            __syncthreads();
            if (t == 0) {
                AST(&ws_f[8 + 2 * (blk - 64)], fminf(fminf(s_small[0], s_small[1]), fminf(s_small[2], s_small[3])));
                AST(&ws_f[9 + 2 * (blk - 64)], fmaxf(fmaxf(s_small[4], s_small[5]), fmaxf(s_small[6], s_small[7])));
            }
        }
    }
    bar_arrive(cnt);

    // ===== Phase B: S1 (blocks 0-63, no dep on A) ; histograms ===============
    if (blk < 64) {
        if (t < 192) {
            int d = t >> 2, kq = t & 3;
            int r = d / 16, c = blk * 16 + (d % 16);
            const float4* bo4 = (const float4*)(bow + r * 1024);
            const float4* go4 = (const float4*)(gow + r * 1024);
            const float4* oa4 = (const float4*)(oaw + c * 1024);
            float s = 0.f;
            for (int k4 = kq * 64; k4 < kq * 64 + 64; ++k4) {
                float4 bv = bo4[k4], gv = go4[k4], wv = oa4[k4];
                s += fabsf(bv.x - gv.x) * wv.x + fabsf(bv.y - gv.y) * wv.y +
                     fabsf(bv.z - gv.z) * wv.z + fabsf(bv.w - gv.w) * wv.w;
            }
            sp[t] = s;
        }
        __syncthreads();
        if (t < 48)
            AST(&S1[(t / 16) * 1024 + blk * 16 + (t % 16)],
                sp[t * 4] + sp[t * 4 + 1] + sp[t * 4 + 2] + sp[t * 4 + 3]);
    }
    bar_wait(cnt, 256);
    {
        int m, b0, nb;
        if (blk < 120)      { m = 0; b0 = blk;       nb = 120; }
        else if (blk < 240) { m = 1; b0 = blk - 120; nb = 120; }
        else if (blk < 248) { m = 2; b0 = blk - 240; nb = 8; }
        else                { m = 3; b0 = blk - 248; nb = 8; }
        const float* p = (m == 0) ? bdw : (m == 1) ? gdw : (m == 2) ? bow : gow;
        int n = (m < 2) ? 1048576 : 3072;
        float lo, hi;
        if (m < 2) {
            float l = ALD(&slots[m * 512 + t]);
            float h = ALD(&slots[m * 512 + 256 + t]);
            for (int off = 32; off; off >>= 1) { l = fminf(l, __shfl_down(l, off)); h = fmaxf(h, __shfl_down(h, off)); }
            if (lane == 0) { s_small[wid] = l; s_small[4 + wid] = h; }
            __syncthreads();
            lo = fminf(fminf(s_small[0], s_small[1]), fminf(s_small[2], s_small[3]));
            hi = fmaxf(fmaxf(s_small[4], s_small[5]), fmaxf(s_small[6], s_small[7]));
        } else {
            lo = ALD(&ws_f[8 + 2 * (m - 2)]);
            hi = ALD(&ws_f[9 + 2 * (m - 2)]);
        }
        // exact f32 bin edges (must match numpy bit-for-bit: 500x amplified)
        float scale = __fdiv_rn(__fsub_rn(hi, lo), 10.0f);
        float lower[NBINS], upper[NBINS];
#pragma unroll
        for (int b = 0; b < NBINS; b++) {
            lower[b] = __fadd_rn(lo, __fmul_rn((float)b, scale));
            upper[b] = __fadd_rn(lower[b], scale);
        }
        unsigned cn[NBINS] = {};
        for (int i = b0 * 256 + t; i < n; i += nb * 256) {
            float v = p[i];
#pragma unroll
            for (int b = 0; b < NBINS; b++)
                if (v >= lower[b] && v < upper[b]) cn[b]++;
        }
        if (t < NBINS) s_hist[t] = 0;
        __syncthreads();
#pragma unroll
        for (int b = 0; b < NBINS; b++)
            if (cn[b]) atomicAdd(&s_hist[b], cn[b]);
        __syncthreads();
        if (t < NBINS && s_hist[t])
            __hip_atomic_fetch_add(&bins[m * NBINS + t], s_hist[t], __ATOMIC_RELAXED, __HIP_MEMORY_SCOPE_AGENT);
    }
    bar_arrive(cnt);

    // ===== Phase C: pu0 GEMM tile + fused h-contribution =====================
    const int bi = ((blk & 7) << 1) | ((blk >> 3) & 1);  // XCD-locality swizzle
    const int bj = blk >> 4;
    f32x4 acc[2][2] = {};
    {
        const int r_ = t >> 2, kc = t & 3;
        const float* pA = bdw + (size_t)(bi * 64 + r_) * 1024 + kc * 8;
        const float* pB = gdw + (size_t)(bi * 64 + r_) * 1024 + kc * 8;
        const float* pW = daw + (size_t)(bj * 64 + r_) * 1024 + kc * 8;
        const int wslot = r_ * 4 + (kc ^ ((r_ >> 1) & 3));
        {
            float4 a0 = ((const float4*)pA)[0], a1 = ((const float4*)pA)[1];
            float4 b0 = ((const float4*)pB)[0], b1 = ((const float4*)pB)[1];
            float4 w0 = ((const float4*)pW)[0], w1 = ((const float4*)pW)[1];
            ((bf8v*)lds_a[0])[wslot] = cvt8abs(a0, a1, b0, b1);
            ((bf8v*)lds_b[0])[wslot] = cvt8(w0, w1);
        }
        __syncthreads();
        int cur = 0;
        for (int tt = 0; tt < 32; ++tt) {
            float4 qa0, qa1, qb0, qb1, qw0, qw1;
            if (tt < 31) {
                int k = (tt + 1) * 32;
                qa0 = ((const float4*)(pA + k))[0]; qa1 = ((const float4*)(pA + k))[1];
                qb0 = ((const float4*)(pB + k))[0]; qb1 = ((const float4*)(pB + k))[1];
                qw0 = ((const float4*)(pW + k))[0]; qw1 = ((const float4*)(pW + k))[1];
            }
            const bf8v* Av = (const bf8v*)lds_a[cur];
            const bf8v* Bv = (const bf8v*)lds_b[cur];
            bf8v a0f = Av[frag_off(wr * 32 + lr, k8)];
            bf8v a1f = Av[frag_off(wr * 32 + 16 + lr, k8)];
            bf8v b0f = Bv[frag_off(wc * 32 + lr, k8)];
            bf8v b1f = Bv[frag_off(wc * 32 + 16 + lr, k8)];
            acc[0][0] = __builtin_amdgcn_mfma_f32_16x16x32_bf16(a0f, b0f, acc[0][0], 0, 0, 0);
            acc[0][1] = __builtin_amdgcn_mfma_f32_16x16x32_bf16(a0f, b1f, acc[0][1], 0, 0, 0);
            acc[1][0] = __builtin_amdgcn_mfma_f32_16x16x32_bf16(a1f, b0f, acc[1][0], 0, 0, 0);
            acc[1][1] = __builtin_amdgcn_mfma_f32_16x16x32_bf16(a1f, b1f, acc[1][1], 0, 0, 0);
            if (tt < 31) {
                ((bf8v*)lds_a[cur ^ 1])[wslot] = cvt8abs(qa0, qa1, qb0, qb1);
                ((bf8v*)lds_b[cur ^ 1])[wslot] = cvt8(qw0, qw1);
            }
            __syncthreads();
            cur ^= 1;
        }
    }
    bar_wait(cnt, 512);  // wg needed only now; hist long done -> near-zero wait
    if (t == 0) {
        float e0 = ent_bins(&bins[0], 1048576.0f);
        float e1 = ent_bins(&bins[10], 1048576.0f);
        float e2 = ent_bins(&bins[20], 3072.0f);
        float e3 = ent_bins(&bins[30], 3072.0f);
        const float API = (float)(0.4 / M_PI);
        s_wg[0] = API * atanf(500.0f * (e0 - e1)) + 0.5f;
        s_wg[1] = API * atanf(500.0f * (e2 - e3)) + 0.5f;
    }
    __syncthreads();
    {   // combine epilogue -> transposed bf16 tile in LDS
        float wg = s_wg[0];
#pragma unroll
        for (int mi = 0; mi < 2; mi++)
#pragma unroll
            for (int mj = 0; mj < 2; mj++)
#pragma unroll
                for (int r = 0; r < 4; r++) {
                    int il = wr * 32 + mi * 16 + k8 * 4 + r;
                    int jl = wc * 32 + mj * 16 + lr;
                    int ig = bi * 64 + il, jg = bj * 64 + jl;
                    float s = acc[mi][mj][r] + dab[jg];
                    float wl = 1.0f / (1.0f + expf(-s));
                    float w = wg * wl + (1.0f - wg);
                    float o = bdw[ig * 1024 + jg] * w + gdw[ig * 1024 + jg] * (1.0f - w);
                    ldsT[il * 72 + jl] = (short)f2bf(o);
                }
        __syncthreads();
        // h-contribution: h_part[m][c in bi-panel] += sum_{j in bj-panel} x0[m][j]*pu0[c][j]
        f32x4 ah[2][2] = {};
#pragma unroll
        for (int ks = 0; ks < 2; ks++) {
            bf8v af[2], bf_[2];
#pragma unroll
            for (int mi = 0; mi < 2; mi++) {
                int m = wr * 32 + mi * 16 + lr;
                const float* xp = x + (size_t)m * 524288 + bj * 64 + ks * 32 + k8 * 8;
                af[mi] = cvt8(((const float4*)xp)[0], ((const float4*)xp)[1]);
            }
#pragma unroll
            for (int mj = 0; mj < 2; mj++) {
                int c = wc * 32 + mj * 16 + lr;
                bf_[mj] = *(const bf8v*)&ldsT[c * 72 + ks * 32 + k8 * 8];
            }
#pragma unroll
            for (int mi = 0; mi < 2; mi++)
#pragma unroll
                for (int mj = 0; mj < 2; mj++)
                    ah[mi][mj] = __builtin_amdgcn_mfma_f32_16x16x32_bf16(af[mi], bf_[mj], ah[mi][mj], 0, 0, 0);
        }
#pragma unroll
        for (int mi = 0; mi < 2; mi++)
#pragma unroll
            for (int mj = 0; mj < 2; mj++)
#pragma unroll
                for (int r = 0; r < 4; r++) {
                    int m = wr * 32 + mi * 16 + k8 * 4 + r;
                    int cg = bi * 64 + wc * 32 + mj * 16 + lr;
                    AST(&part2[((size_t)(bj * 64 + m) << 10) + cg], ah[mi][mj][r]);
                }
    }
    if (blk < 16 && t < 192) {  // pu1 combine
        int r = t >> 6, c = blk * 64 + (t & 63);
        float s1 = ALD(&S1[r * 1024 + c]);
        float wl = 1.0f / (1.0f + expf(-(s1 + oab[c])));
        float wg = s_wg[1];
        float w = wg * wl + (1.0f - wg);
        AST(&pu1[r * 1024 + c], bow[r * 1024 + c] * w + gow[r * 1024 + c] * (1.0f - w));
    }
    bar_arrive(cnt);

    // ===== Phase D: h = tanh(.) ; out = h @ pu1^T + bob ======================
    if (blk < 64) {
        bar_wait(cnt, 768);
        const int m = blk, c0 = t * 4;
        float s0 = 0, s1 = 0, s2 = 0, s3 = 0;
#pragma unroll
        for (int b = 0; b < 16; b++) {
            const float* pp = part2 + ((size_t)(b * 64 + m) << 10) + c0;
            unsigned long long u0 = ALD((const unsigned long long*)pp);
            unsigned long long u1 = ALD((const unsigned long long*)(pp + 2));
            s0 += __uint_as_float((unsigned)u0); s1 += __uint_as_float((unsigned)(u0 >> 32));
            s2 += __uint_as_float((unsigned)u1); s3 += __uint_as_float((unsigned)(u1 >> 32));
        }
        float h0 = tanhf(s0 + bdb[c0]);
        float h1 = tanhf(s1 + bdb[c0 + 1]);
        float h2 = tanhf(s2 + bdb[c0 + 2]);
        float h3 = tanhf(s3 + bdb[c0 + 3]);
        float p0 = 0, p1 = 0, p2 = 0;
#pragma unroll
        for (int l = 0; l < 3; l++) {
            float v = h0 * ALD(&pu1[l * 1024 + c0]) + h1 * ALD(&pu1[l * 1024 + c0 + 1]) +
                      h2 * ALD(&pu1[l * 1024 + c0 + 2]) + h3 * ALD(&pu1[l * 1024 + c0 + 3]);
            if (l == 0) p0 = v; else if (l == 1) p1 = v; else p2 = v;
        }
        for (int off = 32; off; off >>= 1) {
            p0 += __shfl_down(p0, off);
            p1 += __shfl_down(p1, off);
            p2 += __shfl_down(p2, off);
        }
        if (lane == 0) { s_small[wid] = p0; s_small[4 + wid] = p1; s_small[8 + wid] = p2; }
        __syncthreads();
        if (t == 0) {
            out[m * 3 + 0] = s_small[0] + s_small[1] + s_small[2] + s_small[3] + bob[0];
            out[m * 3 + 1] = s_small[4] + s_small[5] + s_small[6] + s_small[7] + bob[1];
            out[m * 3 + 2] = s_small[8] + s_small[9] + s_small[10] + s_small[11] + bob[2];
        }
    }
}

extern "C" void kernel_launch(void* const* d_in, const int* in_sizes, int n_in,
                              void* d_out, int out_size, void* d_ws, size_t ws_size,
                              hipStream_t stream) {
    const float* x   = (const float*)d_in[0];
    const float* bdw = (const float*)d_in[1];
    const float* bdb = (const float*)d_in[2];
    const float* bow = (const float*)d_in[3];
    const float* bob = (const float*)d_in[4];
    const float* gdw = (const float*)d_in[5];
    const float* gow = (const float*)d_in[6];
    const float* daw = (const float*)d_in[7];
    const float* dab = (const float*)d_in[8];
    const float* oaw = (const float*)d_in[9];
    const float* oab = (const float*)d_in[10];
    float* out = (float*)d_out;
    char* ws = (char*)d_ws;

    // zero barrier counter + histogram bins (u32 words 0..63)
    hipMemsetAsync(d_ws, 0, 256, stream);

    void* args[] = {&x, &bdw, &bdb, &bow, &bob, &gdw, &gow, &daw, &dab, &oaw, &oab, &out, &ws};
    hipLaunchCooperativeKernel((const void*)k_mega, dim3(256), dim3(256), args, 0, stream);
}

// Round 6
// 92.138 us; speedup vs baseline: 2.1192x; 1.1460x over previous
//
#include <hip/hip_runtime.h>
#include <hip/hip_bf16.h>
#include <math.h>

// ---------------------------------------------------------------------------
// Single cooperative kernel, 256 blocks x 256 threads. No cache-maintenance
// fences (round 4 lesson) AND no same-address atomic contention (round 5
// lesson: 256 atomicAdd RMWs on one counter serialize ~15-20us/barrier).
// Barrier: per-block flag array (parallel relaxed stores) + all-256-threads
// polling (one flag per thread) + __syncthreads_and.
//
// P-A: per-block minmax partials of bdw,gdw (+bow/gow full minmax)
// S1:  |bow-gow|@oaw^T spread over all 256 blocks (12 dots each)
// P-B: exact-f32 10-bin histograms of bdw,gdw,bow,gow
// P-C: pu0 GEMM 64x64 tile/block (f32->bf16 on the fly, bf16 MFMA, 2-buf),
//      then wg from bins, combine epilogue -> LDS-transposed bf16 tile ->
//      fused 64x64x64 h-contribution MFMA -> coherent f32 partials.
//      Blocks 0-15 combine pu1.
// P-D: blocks 0-63: h = tanh(sum part2 + bdb); out = h @ pu1^T + bob.
//
// All cross-block data via relaxed agent-scope atomics (per-address coherent,
// no L2 walks). Entropy path bit-exact f32 (500x amplified by atan).
//
// ws (f32 words): [8..11] bow/gow minmax; u32[16..55] bins; [64..319] flags
// (memset zeroes words 0..319 each call); [320..1343] minmax slots 4x256;
// [1344..4415] S1 3x1024; [4480..7551] pu1 3x1024; [8192..] part2
// f32[16][64][1024] (4 MB).
// ---------------------------------------------------------------------------

#define NBINS 10
typedef short bf8v __attribute__((ext_vector_type(8)));
typedef float f32x4 __attribute__((ext_vector_type(4)));

#define AST(p, v) __hip_atomic_store((p), (v), __ATOMIC_RELAXED, __HIP_MEMORY_SCOPE_AGENT)
#define ALD(p)    __hip_atomic_load((p), __ATOMIC_RELAXED, __HIP_MEMORY_SCOPE_AGENT)

static __device__ __forceinline__ unsigned short f2bf(float f) {
    __hip_bfloat16 h = __float2bfloat16(f);
    return __builtin_bit_cast(unsigned short, h);
}
static __device__ __forceinline__ bf8v cvt8(float4 a, float4 b) {
    bf8v r;
    r[0] = (short)f2bf(a.x); r[1] = (short)f2bf(a.y); r[2] = (short)f2bf(a.z); r[3] = (short)f2bf(a.w);
    r[4] = (short)f2bf(b.x); r[5] = (short)f2bf(b.y); r[6] = (short)f2bf(b.z); r[7] = (short)f2bf(b.w);
    return r;
}
static __device__ __forceinline__ bf8v cvt8abs(float4 a0, float4 a1, float4 b0, float4 b1) {
    bf8v r;
    r[0] = (short)f2bf(fabsf(a0.x - b0.x)); r[1] = (short)f2bf(fabsf(a0.y - b0.y));
    r[2] = (short)f2bf(fabsf(a0.z - b0.z)); r[3] = (short)f2bf(fabsf(a0.w - b0.w));
    r[4] = (short)f2bf(fabsf(a1.x - b1.x)); r[5] = (short)f2bf(fabsf(a1.y - b1.y));
    r[6] = (short)f2bf(fabsf(a1.z - b1.z)); r[7] = (short)f2bf(fabsf(a1.w - b1.w));
    return r;
}

// Arrival: __syncthreads drains each wave's vmcnt (prior coherent stores ACKed
// at the coherence point) before t0 publishes this block's flag. No RMW, no
// shared hot address across arrivers.
static __device__ __forceinline__ void bar_arrive(unsigned* flags, unsigned phase) {
    __syncthreads();
    if (threadIdx.x == 0) AST(&flags[blockIdx.x], phase);
}
// Wait: thread t polls flags[t] (256 distinct addresses in parallel), block
// proceeds when all flags reached `phase`. ~1 uncached-load round per poll.
static __device__ __forceinline__ void bar_wait(unsigned* flags, unsigned phase) {
    for (;;) {
        unsigned v = ALD(&flags[threadIdx.x]);
        if (__syncthreads_and((int)(v >= phase))) break;
        __builtin_amdgcn_s_sleep(1);
    }
}

static __device__ __forceinline__ int frag_off(int row, int k8) {
    return row * 4 + (k8 ^ ((row >> 1) & 3));  // 16B units, XOR-swizzled
}

static __device__ __forceinline__ float ent_bins(const unsigned* bins, float N) {
    float s = 0.0f;
    for (int b = 0; b < NBINS; b++) {
        float p = __fdiv_rn((float)ALD(&bins[b]), N);
        if (p > 0.0f) s += p * logf(p);
    }
    return -s;
}

__global__ __launch_bounds__(256) void k_mega(
    const float* __restrict__ x, const float* __restrict__ bdw, const float* __restrict__ bdb,
    const float* __restrict__ bow, const float* __restrict__ bob, const float* __restrict__ gdw,
    const float* __restrict__ gow, const float* __restrict__ daw, const float* __restrict__ dab,
    const float* __restrict__ oaw, const float* __restrict__ oab,
    float* __restrict__ out, char* __restrict__ ws) {
    const int blk = blockIdx.x, t = threadIdx.x;
    const int lane = t & 63, wid = t >> 6;
    const int lr = lane & 15, k8 = lane >> 4;
    const int wr = wid >> 1, wc = wid & 1;

    float* ws_f = (float*)ws;
    unsigned* ws_u = (unsigned*)ws;
    unsigned* bins  = ws_u + 16;     // 4x10, zeroed by memset
    unsigned* flags = ws_u + 64;     // 256, zeroed by memset
    float* slots = ws_f + 320;       // 4x256 partial minmax
    float* S1    = ws_f + 1344;      // 3x1024
    float* pu1   = ws_f + 4480;      // 3x1024
    float* part2 = ws_f + 8192;      // [16][64][1024]

    __shared__ short lds_a[2][2048];
    __shared__ short lds_b[2][2048];
    __shared__ short ldsT[64 * 72];
    __shared__ float sp[192];
    __shared__ float s_small[16];
    __shared__ unsigned s_hist[NBINS];
    __shared__ float s_wg[2];

    // ===== Phase A: minmax partials ==========================================
    {
        float lo0 = INFINITY, hi0 = -INFINITY, lo1 = INFINITY, hi1 = -INFINITY;
        int fbase = blk * 1024 + t;
#pragma unroll
        for (int q = 0; q < 4; q++) {
            float4 a = ((const float4*)bdw)[fbase + q * 256];
            float4 b = ((const float4*)gdw)[fbase + q * 256];
            lo0 = fminf(lo0, fminf(fminf(a.x, a.y), fminf(a.z, a.w)));
            hi0 = fmaxf(hi0, fmaxf(fmaxf(a.x, a.y), fmaxf(a.z, a.w)));
            lo1 = fminf(lo1, fminf(fminf(b.x, b.y), fminf(b.z, b.w)));
            hi1 = fmaxf(hi1, fmaxf(fmaxf(b.x, b.y), fmaxf(b.z, b.w)));
        }
        for (int off = 32; off; off >>= 1) {
            lo0 = fminf(lo0, __shfl_down(lo0, off));
            hi0 = fmaxf(hi0, __shfl_down(hi0, off));
            lo1 = fminf(lo1, __shfl_down(lo1, off));
            hi1 = fmaxf(hi1, __shfl_down(hi1, off));
        }
        if (lane == 0) { s_small[wid] = lo0; s_small[4 + wid] = hi0; s_small[8 + wid] = lo1; s_small[12 + wid] = hi1; }
        __syncthreads();
        if (t == 0) {
            AST(&slots[blk],       fminf(fminf(s_small[0], s_small[1]), fminf(s_small[2], s_small[3])));
            AST(&slots[256 + blk], fmaxf(fmaxf(s_small[4], s_small[5]), fmaxf(s_small[6], s_small[7])));
            AST(&slots[512 + blk], fminf(fminf(s_small[8], s_small[9]), fminf(s_small[10], s_small[11])));
            AST(&slots[768 + blk], fmaxf(fmaxf(s_small[12], s_small[13]), fmaxf(s_small[14], s_small[15])));
        }
        if (blk == 64 || blk == 65) {
            const float* p = (blk == 64) ? bow : gow;
            float lo = INFINITY, hi = -INFINITY;
#pragma unroll
            for (int q = 0; q < 12; q++) { float v = p[q * 256 + t]; lo = fminf(lo, v); hi = fmaxf(hi, v); }
            for (int off = 32; off; off >>= 1) { lo = fminf(lo, __shfl_down(lo, off)); hi = fmaxf(hi, __shfl_down(hi, off)); }
            __syncthreads();
            if (lane == 0) { s_small[wid] = lo; s_small[4 + wid] = hi; }
            __syncthreads();
            if (t == 0) {
                AST(&ws_f[8 + 2 * (blk - 64)], fminf(fminf(s_small[0], s_small[1]), fminf(s_small[2], s_small[3])));
                AST(&ws_f[9 + 2 * (blk - 64)], fmaxf(fmaxf(s_small[4], s_small[5]), fmaxf(s_small[6], s_small[7])));
            }
        }
    }
    bar_arrive(flags, 1);

    // ===== S1 = |bow-gow| @ oaw^T, spread over all 256 blocks (12 dots each)
    {
        // t -> dot d = t>>4 (0..11), k-chunk kq = t&15; d -> row r=d>>2, col
        int d = t >> 4, kq = t & 15;
        if (d < 12) {
            int r = d >> 2, c = blk * 4 + (d & 3);
            const float4* bo4 = (const float4*)(bow + r * 1024);
            const float4* go4 = (const float4*)(gow + r * 1024);
            const float4* oa4 = (const float4*)(oaw + c * 1024);
            float s = 0.f;
#pragma unroll
            for (int k4 = kq * 16; k4 < kq * 16 + 16; ++k4) {
                float4 bv = bo4[k4], gv = go4[k4], wv = oa4[k4];
                s += fabsf(bv.x - gv.x) * wv.x + fabsf(bv.y - gv.y) * wv.y +
                     fabsf(bv.z - gv.z) * wv.z + fabsf(bv.w - gv.w) * wv.w;
            }
            sp[t] = s;
        }
        __syncthreads();
        if (t < 12) {
            float s = 0.f;
#pragma unroll
            for (int q = 0; q < 16; q++) s += sp[t * 16 + q];
            AST(&S1[(t >> 2) * 1024 + blk * 4 + (t & 3)], s);
        }
    }
    bar_wait(flags, 1);

    // ===== Phase B: histograms (exact f32 bin arithmetic; bins pre-zeroed)
    {
        int m, b0, nb;
        if (blk < 120)      { m = 0; b0 = blk;       nb = 120; }
        else if (blk < 240) { m = 1; b0 = blk - 120; nb = 120; }
        else if (blk < 248) { m = 2; b0 = blk - 240; nb = 8; }
        else                { m = 3; b0 = blk - 248; nb = 8; }
        const float* p = (m == 0) ? bdw : (m == 1) ? gdw : (m == 2) ? bow : gow;
        int n = (m < 2) ? 1048576 : 3072;
        float lo, hi;
        if (m < 2) {
            float l = ALD(&slots[m * 512 + t]);
            float h = ALD(&slots[m * 512 + 256 + t]);
            for (int off = 32; off; off >>= 1) { l = fminf(l, __shfl_down(l, off)); h = fmaxf(h, __shfl_down(h, off)); }
            if (lane == 0) { s_small[wid] = l; s_small[4 + wid] = h; }
            __syncthreads();
            lo = fminf(fminf(s_small[0], s_small[1]), fminf(s_small[2], s_small[3]));
            hi = fmaxf(fmaxf(s_small[4], s_small[5]), fmaxf(s_small[6], s_small[7]));
        } else {
            lo = ALD(&ws_f[8 + 2 * (m - 2)]);
            hi = ALD(&ws_f[9 + 2 * (m - 2)]);
        }
        // exact f32 bin edges (must match numpy bit-for-bit: 500x amplified)
        float scale = __fdiv_rn(__fsub_rn(hi, lo), 10.0f);
        float lower[NBINS], upper[NBINS];
#pragma unroll
        for (int b = 0; b < NBINS; b++) {
            lower[b] = __fadd_rn(lo, __fmul_rn((float)b, scale));
            upper[b] = __fadd_rn(lower[b], scale);
        }
        unsigned cn[NBINS] = {};
        for (int i = b0 * 256 + t; i < n; i += nb * 256) {
            float v = p[i];
#pragma unroll
            for (int b = 0; b < NBINS; b++)
                if (v >= lower[b] && v < upper[b]) cn[b]++;
        }
        if (t < NBINS) s_hist[t] = 0;
        __syncthreads();
#pragma unroll
        for (int b = 0; b < NBINS; b++)
            if (cn[b]) atomicAdd(&s_hist[b], cn[b]);
        __syncthreads();
        if (t < NBINS && s_hist[t])
            __hip_atomic_fetch_add(&bins[m * NBINS + t], s_hist[t], __ATOMIC_RELAXED, __HIP_MEMORY_SCOPE_AGENT);
    }
    bar_arrive(flags, 2);

    // ===== Phase C: pu0 GEMM tile (no dep on B) + fused h-contribution ======
    const int bi = ((blk & 7) << 1) | ((blk >> 3) & 1);  // XCD-locality swizzle
    const int bj = blk >> 4;
    f32x4 acc[2][2] = {};
    {
        const int r_ = t >> 2, kc = t & 3;
        const float* pA = bdw + (size_t)(bi * 64 + r_) * 1024 + kc * 8;
        const float* pB = gdw + (size_t)(bi * 64 + r_) * 1024 + kc * 8;
        const float* pW = daw + (size_t)(bj * 64 + r_) * 1024 + kc * 8;
        const int wslot = r_ * 4 + (kc ^ ((r_ >> 1) & 3));
        {
            float4 a0 = ((const float4*)pA)[0], a1 = ((const float4*)pA)[1];
            float4 b0 = ((const float4*)pB)[0], b1 = ((const float4*)pB)[1];
            float4 w0 = ((const float4*)pW)[0], w1 = ((const float4*)pW)[1];
            ((bf8v*)lds_a[0])[wslot] = cvt8abs(a0, a1, b0, b1);
            ((bf8v*)lds_b[0])[wslot] = cvt8(w0, w1);
        }
        __syncthreads();
        int cur = 0;
        for (int tt = 0; tt < 32; ++tt) {
            float4 qa0, qa1, qb0, qb1, qw0, qw1;
            if (tt < 31) {
                int k = (tt + 1) * 32;
                qa0 = ((const float4*)(pA + k))[0]; qa1 = ((const float4*)(pA + k))[1];
                qb0 = ((const float4*)(pB + k))[0]; qb1 = ((const float4*)(pB + k))[1];
                qw0 = ((const float4*)(pW + k))[0]; qw1 = ((const float4*)(pW + k))[1];
            }
            const bf8v* Av = (const bf8v*)lds_a[cur];
            const bf8v* Bv = (const bf8v*)lds_b[cur];
            bf8v a0f = Av[frag_off(wr * 32 + lr, k8)];
            bf8v a1f = Av[frag_off(wr * 32 + 16 + lr, k8)];
            bf8v b0f = Bv[frag_off(wc * 32 + lr, k8)];
            bf8v b1f = Bv[frag_off(wc * 32 + 16 + lr, k8)];
            acc[0][0] = __builtin_amdgcn_mfma_f32_16x16x32_bf16(a0f, b0f, acc[0][0], 0, 0, 0);
            acc[0][1] = __builtin_amdgcn_mfma_f32_16x16x32_bf16(a0f, b1f, acc[0][1], 0, 0, 0);
            acc[1][0] = __builtin_amdgcn_mfma_f32_16x16x32_bf16(a1f, b0f, acc[1][0], 0, 0, 0);
            acc[1][1] = __builtin_amdgcn_mfma_f32_16x16x32_bf16(a1f, b1f, acc[1][1], 0, 0, 0);
            if (tt < 31) {
                ((bf8v*)lds_a[cur ^ 1])[wslot] = cvt8abs(qa0, qa1, qb0, qb1);
                ((bf8v*)lds_b[cur ^ 1])[wslot] = cvt8(qw0, qw1);
            }
            __syncthreads();
            cur ^= 1;
        }
    }
    bar_wait(flags, 2);  // bins long done -> near-zero wait
    if (t == 0) {
        float e0 = ent_bins(&bins[0], 1048576.0f);
        float e1 = ent_bins(&bins[10], 1048576.0f);
        float e2 = ent_bins(&bins[20], 3072.0f);
        float e3 = ent_bins(&bins[30], 3072.0f);
        const float API = (float)(0.4 / M_PI);
        s_wg[0] = API * atanf(500.0f * (e0 - e1)) + 0.5f;
        s_wg[1] = API * atanf(500.0f * (e2 - e3)) + 0.5f;
    }
    __syncthreads();
    {   // combine epilogue -> transposed bf16 tile in LDS
        float wg = s_wg[0];
#pragma unroll
        for (int mi = 0; mi < 2; mi++)
#pragma unroll
            for (int mj = 0; mj < 2; mj++)
#pragma unroll
                for (int r = 0; r < 4; r++) {
                    int il = wr * 32 + mi * 16 + k8 * 4 + r;
                    int jl = wc * 32 + mj * 16 + lr;
                    int ig = bi * 64 + il, jg = bj * 64 + jl;
                    float s = acc[mi][mj][r] + dab[jg];
                    float wl = 1.0f / (1.0f + expf(-s));
                    float w = wg * wl + (1.0f - wg);
                    float o = bdw[ig * 1024 + jg] * w + gdw[ig * 1024 + jg] * (1.0f - w);
                    ldsT[il * 72 + jl] = (short)f2bf(o);
                }
        __syncthreads();
        // h-contribution: part2[bj][m][bi-panel c] = sum_{j in bj-panel} x0[m][j]*pu0[c][j]
        f32x4 ah[2][2] = {};
#pragma unroll
        for (int ks = 0; ks < 2; ks++) {
            bf8v af[2], bf_[2];
#pragma unroll
            for (int mi = 0; mi < 2; mi++) {
                int m = wr * 32 + mi * 16 + lr;
                const float* xp = x + (size_t)m * 524288 + bj * 64 + ks * 32 + k8 * 8;
                af[mi] = cvt8(((const float4*)xp)[0], ((const float4*)xp)[1]);
            }
#pragma unroll
            for (int mj = 0; mj < 2; mj++) {
                int c = wc * 32 + mj * 16 + lr;
                bf_[mj] = *(const bf8v*)&ldsT[c * 72 + ks * 32 + k8 * 8];
            }
#pragma unroll
            for (int mi = 0; mi < 2; mi++)
#pragma unroll
                for (int mj = 0; mj < 2; mj++)
                    ah[mi][mj] = __builtin_amdgcn_mfma_f32_16x16x32_bf16(af[mi], bf_[mj], ah[mi][mj], 0, 0, 0);
        }
#pragma unroll
        for (int mi = 0; mi < 2; mi++)
#pragma unroll
            for (int mj = 0; mj < 2; mj++)
#pragma unroll
                for (int r = 0; r < 4; r++) {
                    int m = wr * 32 + mi * 16 + k8 * 4 + r;
                    int cg = bi * 64 + wc * 32 + mj * 16 + lr;
                    AST(&part2[((size_t)(bj * 64 + m) << 10) + cg], ah[mi][mj][r]);
                }
    }
    if (blk < 16 && t < 192) {  // pu1 combine
        int r = t >> 6, c = blk * 64 + (t & 63);
        float s1 = ALD(&S1[r * 1024 + c]);
        float wl = 1.0f / (1.0f + expf(-(s1 + oab[c])));
        float wg = s_wg[1];
        float w = wg * wl + (1.0f - wg);
        AST(&pu1[r * 1024 + c], bow[r * 1024 + c] * w + gow[r * 1024 + c] * (1.0f - w));
    }
    bar_arrive(flags, 3);

    // ===== Phase D: h = tanh(.) ; out = h @ pu1^T + bob ======================
    if (blk < 64) {
        bar_wait(flags, 3);
        const int m = blk, c0 = t * 4;
        float s0 = 0, s1 = 0, s2 = 0, s3 = 0;
#pragma unroll
        for (int b = 0; b < 16; b++) {
            const float* pp = part2 + ((size_t)(b * 64 + m) << 10) + c0;
            unsigned long long u0 = ALD((const unsigned long long*)pp);
            unsigned long long u1 = ALD((const unsigned long long*)(pp + 2));
            s0 += __uint_as_float((unsigned)u0); s1 += __uint_as_float((unsigned)(u0 >> 32));
            s2 += __uint_as_float((unsigned)u1); s3 += __uint_as_float((unsigned)(u1 >> 32));
        }
        float h0 = tanhf(s0 + bdb[c0]);
        float h1 = tanhf(s1 + bdb[c0 + 1]);
        float h2 = tanhf(s2 + bdb[c0 + 2]);
        float h3 = tanhf(s3 + bdb[c0 + 3]);
        float p0 = 0, p1 = 0, p2 = 0;
#pragma unroll
        for (int l = 0; l < 3; l++) {
            float v = h0 * ALD(&pu1[l * 1024 + c0]) + h1 * ALD(&pu1[l * 1024 + c0 + 1]) +
                      h2 * ALD(&pu1[l * 1024 + c0 + 2]) + h3 * ALD(&pu1[l * 1024 + c0 + 3]);
            if (l == 0) p0 = v; else if (l == 1) p1 = v; else p2 = v;
        }
        for (int off = 32; off; off >>= 1) {
            p0 += __shfl_down(p0, off);
            p1 += __shfl_down(p1, off);
            p2 += __shfl_down(p2, off);
        }
        if (lane == 0) { s_small[wid] = p0; s_small[4 + wid] = p1; s_small[8 + wid] = p2; }
        __syncthreads();
        if (t == 0) {
            out[m * 3 + 0] = s_small[0] + s_small[1] + s_small[2] + s_small[3] + bob[0];
            out[m * 3 + 1] = s_small[4] + s_small[5] + s_small[6] + s_small[7] + bob[1];
            out[m * 3 + 2] = s_small[8] + s_small[9] + s_small[10] + s_small[11] + bob[2];
        }
    }
}

extern "C" void kernel_launch(void* const* d_in, const int* in_sizes, int n_in,
                              void* d_out, int out_size, void* d_ws, size_t ws_size,
                              hipStream_t stream) {
    const float* x   = (const float*)d_in[0];
    const float* bdw = (const float*)d_in[1];
    const float* bdb = (const float*)d_in[2];
    const float* bow = (const float*)d_in[3];
    const float* bob = (const float*)d_in[4];
    const float* gdw = (const float*)d_in[5];
    const float* gow = (const float*)d_in[6];
    const float* daw = (const float*)d_in[7];
    const float* dab = (const float*)d_in[8];
    const float* oaw = (const float*)d_in[9];
    const float* oab = (const float*)d_in[10];
    float* out = (float*)d_out;
    char* ws = (char*)d_ws;

    // zero words 0..319: misc(16) + bins(40) + flags(256)
    hipMemsetAsync(d_ws, 0, 1280, stream);

    void* args[] = {&x, &bdw, &bdb, &bow, &bob, &gdw, &gow, &daw, &dab, &oaw, &oab, &out, &ws};
    hipLaunchCooperativeKernel((const void*)k_mega, dim3(256), dim3(256), args, 0, stream);
}

// Round 7
// 59.205 us; speedup vs baseline: 3.2980x; 1.5563x over previous
//
#include <hip/hip_runtime.h>
#include <hip/hip_bf16.h>
#include <math.h>

// ---------------------------------------------------------------------------
// 3-kernel chain. Kernel boundaries provide cross-XCD coherence, so all bulk
// intermediates use PLAIN vectorized cached stores (round 5/6 lesson: bulk
// data through scalar agent-scope atomics = 1M serialized fabric ops).
//
// K1 k_prep (512 blocks): Db=|bdw-gdw| bf16, Wb=daw bf16, x0b=x[:,0,:] bf16,
//    per-block minmax partials of bdw/gdw, bow/gow minmax, S1=|bow-gow|@oaw^T
//    partial dots, zero flags+bins.
// K2 k_main (256 blocks): exact-f32 histograms (global minmax from partials)
//    -> flag arrive; pu0 64x64-tile MFMA GEMM staged from Db/Wb via
//    global_load_lds; flag wait (lands after GEMM -> ~free); wg from bins;
//    combine epilogue -> LDS-transposed bf16 tile -> fused 64x64x64
//    h-contribution MFMA -> part2 plain stores. Blocks 0-15: pu1 combine.
// K3 k_out (64 blocks): h = tanh(sum part2 + bdb); out = h @ pu1^T + bob.
//
// Entropy path stays bit-exact f32 (500x amplified by atan).
//
// ws byte layout:
//   f32[8..11]  bow/gow minmax        u32[16..55]  bins
//   u32[64..319] flags                f32[320..1343] minmax slots 4x256
//   f32[1344..4415] S1 3x1024         f32[4480..7551] pu1 3x1024
//   f32[8192..1056767] part2 [16][64][1024] (4 MB)
//   byte 4227072: Db bf16 1Mx2B       byte 6324224: Wb bf16
//   byte 8421376: x0b bf16 64x1024
// ---------------------------------------------------------------------------

#define NBINS 10
typedef short bf8v __attribute__((ext_vector_type(8)));
typedef float f32x4 __attribute__((ext_vector_type(4)));

#define AST(p, v) __hip_atomic_store((p), (v), __ATOMIC_RELAXED, __HIP_MEMORY_SCOPE_AGENT)
#define ALD(p)    __hip_atomic_load((p), __ATOMIC_RELAXED, __HIP_MEMORY_SCOPE_AGENT)

static __device__ __forceinline__ unsigned short f2bf(float f) {
    __hip_bfloat16 h = __float2bfloat16(f);
    return __builtin_bit_cast(unsigned short, h);
}

#define GL2LDS(gp, lp) __builtin_amdgcn_global_load_lds(                       \
    (__attribute__((address_space(1))) void*)(gp),                             \
    (__attribute__((address_space(3))) void*)(lp), 16, 0, 0)

static __device__ __forceinline__ void stage_tile(const unsigned short* __restrict__ src,
                                                  short* lds_tile, int t, int row0, int k0) {
    int r = t >> 2, s = t & 3;
    int kg = s ^ ((r >> 1) & 3);
    GL2LDS(src + (size_t)(row0 + r) * 1024 + k0 + kg * 8, lds_tile + t * 8);
}

static __device__ __forceinline__ int frag_off(int row, int k8) {
    return row * 4 + (k8 ^ ((row >> 1) & 3));  // 16B units, XOR-swizzled
}

static __device__ __forceinline__ float ent_bins(const unsigned* bins, float N) {
    float s = 0.0f;
    for (int b = 0; b < NBINS; b++) {
        float p = __fdiv_rn((float)ALD(&bins[b]), N);
        if (p > 0.0f) s += p * logf(p);
    }
    return -s;
}

// =============================== K1 =========================================
__global__ __launch_bounds__(256) void k_prep(
    const float* __restrict__ x, const float* __restrict__ bdw, const float* __restrict__ bow,
    const float* __restrict__ gdw, const float* __restrict__ gow, const float* __restrict__ daw,
    const float* __restrict__ oaw, char* __restrict__ ws) {
    const int blk = blockIdx.x, t = threadIdx.x;
    const int lane = t & 63, wid = t >> 6;
    float* ws_f = (float*)ws;
    unsigned* ws_u = (unsigned*)ws;
    float* slots = ws_f + 320;
    float* S1    = ws_f + 1344;
    unsigned short* Db  = (unsigned short*)(ws + 4227072);
    unsigned short* Wb  = (unsigned short*)(ws + 6324224);
    unsigned short* x0b = (unsigned short*)(ws + 8421376);
    __shared__ float sp[256];
    __shared__ float s_small[16];

    if (blk < 256) {
        // conv to bf16 + minmax partials
        float lo0 = INFINITY, hi0 = -INFINITY, lo1 = INFINITY, hi1 = -INFINITY;
        int fbase = blk * 1024 + t;
#pragma unroll
        for (int q = 0; q < 4; q++) {
            int idx = fbase + q * 256;
            float4 a = ((const float4*)bdw)[idx];
            float4 b = ((const float4*)gdw)[idx];
            float4 w = ((const float4*)daw)[idx];
            lo0 = fminf(lo0, fminf(fminf(a.x, a.y), fminf(a.z, a.w)));
            hi0 = fmaxf(hi0, fmaxf(fmaxf(a.x, a.y), fmaxf(a.z, a.w)));
            lo1 = fminf(lo1, fminf(fminf(b.x, b.y), fminf(b.z, b.w)));
            hi1 = fmaxf(hi1, fmaxf(fmaxf(b.x, b.y), fmaxf(b.z, b.w)));
            ushort4 d, ww;
            d.x = f2bf(fabsf(a.x - b.x)); d.y = f2bf(fabsf(a.y - b.y));
            d.z = f2bf(fabsf(a.z - b.z)); d.w = f2bf(fabsf(a.w - b.w));
            ww.x = f2bf(w.x); ww.y = f2bf(w.y); ww.z = f2bf(w.z); ww.w = f2bf(w.w);
            ((ushort4*)Db)[idx] = d;
            ((ushort4*)Wb)[idx] = ww;
        }
        for (int off = 32; off; off >>= 1) {
            lo0 = fminf(lo0, __shfl_down(lo0, off));
            hi0 = fmaxf(hi0, __shfl_down(hi0, off));
            lo1 = fminf(lo1, __shfl_down(lo1, off));
            hi1 = fmaxf(hi1, __shfl_down(hi1, off));
        }
        if (lane == 0) { s_small[wid] = lo0; s_small[4 + wid] = hi0; s_small[8 + wid] = lo1; s_small[12 + wid] = hi1; }
        __syncthreads();
        if (t == 0) {
            slots[blk]       = fminf(fminf(s_small[0], s_small[1]), fminf(s_small[2], s_small[3]));
            slots[256 + blk] = fmaxf(fmaxf(s_small[4], s_small[5]), fmaxf(s_small[6], s_small[7]));
            slots[512 + blk] = fminf(fminf(s_small[8], s_small[9]), fminf(s_small[10], s_small[11]));
            slots[768 + blk] = fmaxf(fmaxf(s_small[12], s_small[13]), fmaxf(s_small[14], s_small[15]));
        }
    } else {
        const int blk2 = blk - 256;
        // S1 partial dots: 12 dots of 1024 per block
        {
            int d = t >> 4, kq = t & 15;
            if (d < 12) {
                int r = d >> 2, c = blk2 * 4 + (d & 3);
                const float4* bo4 = (const float4*)(bow + r * 1024);
                const float4* go4 = (const float4*)(gow + r * 1024);
                const float4* oa4 = (const float4*)(oaw + c * 1024);
                float s = 0.f;
#pragma unroll
                for (int k4 = kq * 16; k4 < kq * 16 + 16; ++k4) {
                    float4 bv = bo4[k4], gv = go4[k4], wv = oa4[k4];
                    s += fabsf(bv.x - gv.x) * wv.x + fabsf(bv.y - gv.y) * wv.y +
                         fabsf(bv.z - gv.z) * wv.z + fabsf(bv.w - gv.w) * wv.w;
                }
                sp[t] = s;
            }
            __syncthreads();
            if (t < 12) {
                float s = 0.f;
#pragma unroll
                for (int q = 0; q < 16; q++) s += sp[t * 16 + q];
                S1[(t >> 2) * 1024 + blk2 * 4 + (t & 3)] = s;
            }
        }
        if (blk == 256 || blk == 257) {  // bow/gow minmax
            const float* p = (blk == 256) ? bow : gow;
            float lo = INFINITY, hi = -INFINITY;
#pragma unroll
            for (int q = 0; q < 12; q++) { float v = p[q * 256 + t]; lo = fminf(lo, v); hi = fmaxf(hi, v); }
            for (int off = 32; off; off >>= 1) { lo = fminf(lo, __shfl_down(lo, off)); hi = fmaxf(hi, __shfl_down(hi, off)); }
            __syncthreads();
            if (lane == 0) { s_small[wid] = lo; s_small[4 + wid] = hi; }
            __syncthreads();
            if (t == 0) {
                ws_f[8 + 2 * (blk - 256)] = fminf(fminf(s_small[0], s_small[1]), fminf(s_small[2], s_small[3]));
                ws_f[9 + 2 * (blk - 256)] = fmaxf(fmaxf(s_small[4], s_small[5]), fmaxf(s_small[6], s_small[7]));
            }
        }
        if (blk == 258) {  // zero flags (u32[64..319]) + bins (u32[16..55])
            ws_u[64 + t] = 0u;
            if (t < 40) ws_u[16 + t] = 0u;
        }
        if (blk >= 260 && blk < 324) {  // x0b rows
            int row = blk - 260;
            float4 v = ((const float4*)(x + (size_t)row * 524288))[t];
            ushort4 o; o.x = f2bf(v.x); o.y = f2bf(v.y); o.z = f2bf(v.z); o.w = f2bf(v.w);
            ((ushort4*)x0b)[row * 256 + t] = o;
        }
    }
}

// =============================== K2 =========================================
__global__ __launch_bounds__(256) void k_main(
    const float* __restrict__ bdw, const float* __restrict__ gdw, const float* __restrict__ dab,
    const float* __restrict__ bow, const float* __restrict__ gow, const float* __restrict__ oab,
    char* __restrict__ ws) {
    const int blk = blockIdx.x, t = threadIdx.x;
    const int lane = t & 63, wid = t >> 6;
    const int lr = lane & 15, k8 = lane >> 4;
    const int wr = wid >> 1, wc = wid & 1;

    float* ws_f = (float*)ws;
    unsigned* ws_u = (unsigned*)ws;
    unsigned* bins  = ws_u + 16;
    unsigned* flags = ws_u + 64;
    float* slots = ws_f + 320;
    float* S1    = ws_f + 1344;
    float* pu1   = ws_f + 4480;
    float* part2 = ws_f + 8192;
    const unsigned short* Db  = (const unsigned short*)(ws + 4227072);
    const unsigned short* Wb  = (const unsigned short*)(ws + 6324224);
    const unsigned short* x0b = (const unsigned short*)(ws + 8421376);

    __shared__ short lds_a[2][2048];
    __shared__ short lds_b[2][2048];
    __shared__ short ldsT[64 * 72];
    __shared__ float s_small[16];
    __shared__ unsigned s_hist[NBINS];
    __shared__ float s_wg[2];

    // ---- histograms (exact f32 bin arithmetic) ----
    {
        int m, b0, nb;
        if (blk < 120)      { m = 0; b0 = blk;       nb = 120; }
        else if (blk < 240) { m = 1; b0 = blk - 120; nb = 120; }
        else if (blk < 248) { m = 2; b0 = blk - 240; nb = 8; }
        else                { m = 3; b0 = blk - 248; nb = 8; }
        const float* p = (m == 0) ? bdw : (m == 1) ? gdw : (m == 2) ? bow : gow;
        int n = (m < 2) ? 1048576 : 3072;
        float lo, hi;
        if (m < 2) {
            float l = slots[m * 512 + t];
            float h = slots[m * 512 + 256 + t];
            for (int off = 32; off; off >>= 1) { l = fminf(l, __shfl_down(l, off)); h = fmaxf(h, __shfl_down(h, off)); }
            if (lane == 0) { s_small[wid] = l; s_small[4 + wid] = h; }
            __syncthreads();
            lo = fminf(fminf(s_small[0], s_small[1]), fminf(s_small[2], s_small[3]));
            hi = fmaxf(fmaxf(s_small[4], s_small[5]), fmaxf(s_small[6], s_small[7]));
        } else {
            lo = ws_f[8 + 2 * (m - 2)];
            hi = ws_f[9 + 2 * (m - 2)];
        }
        float scale = __fdiv_rn(__fsub_rn(hi, lo), 10.0f);
        float lower[NBINS], upper[NBINS];
#pragma unroll
        for (int b = 0; b < NBINS; b++) {
            lower[b] = __fadd_rn(lo, __fmul_rn((float)b, scale));
            upper[b] = __fadd_rn(lower[b], scale);
        }
        unsigned cn[NBINS] = {};
        for (int i = b0 * 256 + t; i < n; i += nb * 256) {
            float v = p[i];
#pragma unroll
            for (int b = 0; b < NBINS; b++)
                if (v >= lower[b] && v < upper[b]) cn[b]++;
        }
        if (t < NBINS) s_hist[t] = 0;
        __syncthreads();
#pragma unroll
        for (int b = 0; b < NBINS; b++)
            if (cn[b]) atomicAdd(&s_hist[b], cn[b]);
        __syncthreads();
        if (t < NBINS && s_hist[t])
            __hip_atomic_fetch_add(&bins[m * NBINS + t], s_hist[t], __ATOMIC_RELAXED, __HIP_MEMORY_SCOPE_AGENT);
    }
    // arrive: __syncthreads drains the atomic adds before t0 publishes
    __syncthreads();
    if (t == 0) AST(&flags[blk], 1u);

    // ---- pu0 GEMM: 64x64 tile, staged from bf16 via global_load_lds ----
    const int bi = ((blk & 7) << 1) | ((blk >> 3) & 1);  // XCD-locality swizzle
    const int bj = blk >> 4;
    f32x4 acc[2][2] = {};
    {
        stage_tile(Db, lds_a[0], t, bi * 64, 0);
        stage_tile(Wb, lds_b[0], t, bj * 64, 0);
        int cur = 0;
        for (int tt = 0; tt < 32; ++tt) {
            __syncthreads();  // drains gl2lds vmcnt -> staged tile visible
            if (tt + 1 < 32) {
                stage_tile(Db, lds_a[cur ^ 1], t, bi * 64, (tt + 1) * 32);
                stage_tile(Wb, lds_b[cur ^ 1], t, bj * 64, (tt + 1) * 32);
            }
            const bf8v* Av = (const bf8v*)lds_a[cur];
            const bf8v* Bv = (const bf8v*)lds_b[cur];
            bf8v a0 = Av[frag_off(wr * 32 + lr, k8)];
            bf8v a1 = Av[frag_off(wr * 32 + 16 + lr, k8)];
            bf8v b0 = Bv[frag_off(wc * 32 + lr, k8)];
            bf8v b1 = Bv[frag_off(wc * 32 + 16 + lr, k8)];
            acc[0][0] = __builtin_amdgcn_mfma_f32_16x16x32_bf16(a0, b0, acc[0][0], 0, 0, 0);
            acc[0][1] = __builtin_amdgcn_mfma_f32_16x16x32_bf16(a0, b1, acc[0][1], 0, 0, 0);
            acc[1][0] = __builtin_amdgcn_mfma_f32_16x16x32_bf16(a1, b0, acc[1][0], 0, 0, 0);
            acc[1][1] = __builtin_amdgcn_mfma_f32_16x16x32_bf16(a1, b1, acc[1][1], 0, 0, 0);
            cur ^= 1;
        }
    }

    // ---- wait for all histograms (long done by now), compute wg ----
    for (;;) {
        unsigned v = ALD(&flags[t]);
        if (__syncthreads_and((int)(v >= 1u))) break;
        __builtin_amdgcn_s_sleep(1);
    }
    if (t == 0) {
        float e0 = ent_bins(&bins[0], 1048576.0f);
        float e1 = ent_bins(&bins[10], 1048576.0f);
        float e2 = ent_bins(&bins[20], 3072.0f);
        float e3 = ent_bins(&bins[30], 3072.0f);
        const float API = (float)(0.4 / M_PI);
        s_wg[0] = API * atanf(500.0f * (e0 - e1)) + 0.5f;
        s_wg[1] = API * atanf(500.0f * (e2 - e3)) + 0.5f;
    }
    __syncthreads();

    // ---- combine epilogue -> transposed bf16 tile in LDS ----
    {
        float wg = s_wg[0];
#pragma unroll
        for (int mi = 0; mi < 2; mi++)
#pragma unroll
            for (int mj = 0; mj < 2; mj++)
#pragma unroll
                for (int r = 0; r < 4; r++) {
                    int il = wr * 32 + mi * 16 + k8 * 4 + r;
                    int jl = wc * 32 + mj * 16 + lr;
                    int ig = bi * 64 + il, jg = bj * 64 + jl;
                    float s = acc[mi][mj][r] + dab[jg];
                    float wl = 1.0f / (1.0f + expf(-s));
                    float w = wg * wl + (1.0f - wg);
                    float o = bdw[ig * 1024 + jg] * w + gdw[ig * 1024 + jg] * (1.0f - w);
                    ldsT[il * 72 + jl] = (short)f2bf(o);
                }
        __syncthreads();
        // fused h-contribution: part2[bj][m][c in bi-panel]
        f32x4 ah[2][2] = {};
#pragma unroll
        for (int ks = 0; ks < 2; ks++) {
            bf8v af[2], bf_[2];
#pragma unroll
            for (int mi = 0; mi < 2; mi++) {
                int m = wr * 32 + mi * 16 + lr;
                af[mi] = *(const bf8v*)&x0b[m * 1024 + bj * 64 + ks * 32 + k8 * 8];
            }
#pragma unroll
            for (int mj = 0; mj < 2; mj++) {
                int c = wc * 32 + mj * 16 + lr;
                bf_[mj] = *(const bf8v*)&ldsT[c * 72 + ks * 32 + k8 * 8];
            }
#pragma unroll
            for (int mi = 0; mi < 2; mi++)
#pragma unroll
                for (int mj = 0; mj < 2; mj++)
                    ah[mi][mj] = __builtin_amdgcn_mfma_f32_16x16x32_bf16(af[mi], bf_[mj], ah[mi][mj], 0, 0, 0);
        }
#pragma unroll
        for (int mi = 0; mi < 2; mi++)
#pragma unroll
            for (int mj = 0; mj < 2; mj++)
#pragma unroll
                for (int r = 0; r < 4; r++) {
                    int m = wr * 32 + mi * 16 + k8 * 4 + r;
                    int cg = bi * 64 + wc * 32 + mj * 16 + lr;
                    part2[((size_t)(bj * 64 + m) << 10) + cg] = ah[mi][mj][r];  // plain store
                }
    }
    if (blk < 16 && t < 192) {  // pu1 combine
        int r = t >> 6, c = blk * 64 + (t & 63);
        float s1 = S1[r * 1024 + c];
        float wl = 1.0f / (1.0f + expf(-(s1 + oab[c])));
        float wg = s_wg[1];
        float w = wg * wl + (1.0f - wg);
        pu1[r * 1024 + c] = bow[r * 1024 + c] * w + gow[r * 1024 + c] * (1.0f - w);
    }
}

// =============================== K3 =========================================
__global__ __launch_bounds__(256) void k_out(
    const float* __restrict__ bdb, const float* __restrict__ bob,
    float* __restrict__ out, const char* __restrict__ ws) {
    const int m = blockIdx.x, t = threadIdx.x;
    const int lane = t & 63, wid = t >> 6;
    const float* ws_f = (const float*)ws;
    const float* pu1   = ws_f + 4480;
    const float* part2 = ws_f + 8192;
    __shared__ float s_small[16];

    const int c0 = t * 4;
    f32x4 s = {0.f, 0.f, 0.f, 0.f};
#pragma unroll
    for (int b = 0; b < 16; b++)
        s += *(const f32x4*)(part2 + ((size_t)(b * 64 + m) << 10) + c0);
    float h0 = tanhf(s[0] + bdb[c0]);
    float h1 = tanhf(s[1] + bdb[c0 + 1]);
    float h2 = tanhf(s[2] + bdb[c0 + 2]);
    float h3 = tanhf(s[3] + bdb[c0 + 3]);
    float p0, p1, p2;
    {
        f32x4 q0 = *(const f32x4*)(pu1 + c0);
        f32x4 q1 = *(const f32x4*)(pu1 + 1024 + c0);
        f32x4 q2 = *(const f32x4*)(pu1 + 2048 + c0);
        p0 = h0 * q0[0] + h1 * q0[1] + h2 * q0[2] + h3 * q0[3];
        p1 = h0 * q1[0] + h1 * q1[1] + h2 * q1[2] + h3 * q1[3];
        p2 = h0 * q2[0] + h1 * q2[1] + h2 * q2[2] + h3 * q2[3];
    }
    for (int off = 32; off; off >>= 1) {
        p0 += __shfl_down(p0, off);
        p1 += __shfl_down(p1, off);
        p2 += __shfl_down(p2, off);
    }
    if (lane == 0) { s_small[wid] = p0; s_small[4 + wid] = p1; s_small[8 + wid] = p2; }
    __syncthreads();
    if (t == 0) {
        out[m * 3 + 0] = s_small[0] + s_small[1] + s_small[2] + s_small[3] + bob[0];
        out[m * 3 + 1] = s_small[4] + s_small[5] + s_small[6] + s_small[7] + bob[1];
        out[m * 3 + 2] = s_small[8] + s_small[9] + s_small[10] + s_small[11] + bob[2];
    }
}

extern "C" void kernel_launch(void* const* d_in, const int* in_sizes, int n_in,
                              void* d_out, int out_size, void* d_ws, size_t ws_size,
                              hipStream_t stream) {
    const float* x   = (const float*)d_in[0];
    const float* bdw = (const float*)d_in[1];
    const float* bdb = (const float*)d_in[2];
    const float* bow = (const float*)d_in[3];
    const float* bob = (const float*)d_in[4];
    const float* gdw = (const float*)d_in[5];
    const float* gow = (const float*)d_in[6];
    const float* daw = (const float*)d_in[7];
    const float* dab = (const float*)d_in[8];
    const float* oaw = (const float*)d_in[9];
    const float* oab = (const float*)d_in[10];
    float* out = (float*)d_out;
    char* ws = (char*)d_ws;

    k_prep<<<512, 256, 0, stream>>>(x, bdw, bow, gdw, gow, daw, oaw, ws);
    k_main<<<256, 256, 0, stream>>>(bdw, gdw, dab, bow, gow, oab, ws);
    k_out<<<64, 256, 0, stream>>>(bdb, bob, out, ws);
}

// Round 8
// 55.288 us; speedup vs baseline: 3.5316x; 1.0708x over previous
//
#include <hip/hip_runtime.h>
#include <hip/hip_bf16.h>
#include <math.h>

// ---------------------------------------------------------------------------
// 3-kernel chain (kernel boundaries = cheapest cross-XCD coherence).
// K1 k_prep (512): Db=|bdw-gdw| bf16, Wb=daw bf16, x0b, minmax partials,
//    S1=|bow-gow|@oaw^T partial dots, zero flags+bins.
// K2 k_main (512, 2 blocks/CU): exact-f32 histograms -> flag; pu0 GEMM
//    32x64-tile (BK=64, gl2lds double-buffer, XCD-neighborhood swizzle:
//    each XCD's panels L2-resident); flag-wait (free, lands after GEMM);
//    wg; combine epilogue -> ldsT -> fused h-contribution MFMA -> part2.
//    Blocks 0-15: pu1 combine.
// K3 k_out (64): h = tanh(sum part2 + bdb); out = h @ pu1^T + bob.
// Entropy path bit-exact f32 (500x amplified by atan).
//
// ws (f32 words): [8..11] bow/gow minmax; u32[16..55] bins; u32[64..575]
// flags(512); [576..1599] minmax slots 4x256; [1600..4671] S1; [4736..7807]
// pu1; [8192..1056767] part2 [16][64][1024].
// bytes: Db @4227072, Wb @6324224, x0b @8421376.
// ---------------------------------------------------------------------------

#define NBINS 10
typedef short bf8v __attribute__((ext_vector_type(8)));
typedef float f32x4 __attribute__((ext_vector_type(4)));

#define AST(p, v) __hip_atomic_store((p), (v), __ATOMIC_RELAXED, __HIP_MEMORY_SCOPE_AGENT)
#define ALD(p)    __hip_atomic_load((p), __ATOMIC_RELAXED, __HIP_MEMORY_SCOPE_AGENT)

static __device__ __forceinline__ unsigned short f2bf(float f) {
    __hip_bfloat16 h = __float2bfloat16(f);
    return __builtin_bit_cast(unsigned short, h);
}

#define GL2LDS(gp, lp) __builtin_amdgcn_global_load_lds(                       \
    (__attribute__((address_space(1))) void*)(gp),                             \
    (__attribute__((address_space(3))) void*)(lp), 16, 0, 0)

// Stage one 16B slot per thread: slot s -> row s>>3, k-group (s&7)^(row&7)
// (XOR swizzle on the GLOBAL source; LDS stays linear per gl2lds rules).
static __device__ __forceinline__ void stage_slot(const unsigned short* __restrict__ src,
                                                  short* dst, int s, int row0, int k0) {
    int r = s >> 3, g = (s & 7) ^ (r & 7);
    GL2LDS(src + (size_t)(row0 + r) * 1024 + k0 + g * 8, dst + s * 8);
}
// Fragment read: global k-group G of row -> slot G^(row&7)
static __device__ __forceinline__ bf8v fr(const short* lds, int row, int G) {
    return ((const bf8v*)lds)[row * 8 + (G ^ (row & 7))];
}

static __device__ __forceinline__ float ent_bins(const unsigned* bins, float N) {
    float s = 0.0f;
    for (int b = 0; b < NBINS; b++) {
        float p = __fdiv_rn((float)ALD(&bins[b]), N);
        if (p > 0.0f) s += p * logf(p);
    }
    return -s;
}

// =============================== K1 =========================================
__global__ __launch_bounds__(256) void k_prep(
    const float* __restrict__ x, const float* __restrict__ bdw, const float* __restrict__ bow,
    const float* __restrict__ gdw, const float* __restrict__ gow, const float* __restrict__ daw,
    const float* __restrict__ oaw, char* __restrict__ ws) {
    const int blk = blockIdx.x, t = threadIdx.x;
    const int lane = t & 63, wid = t >> 6;
    float* ws_f = (float*)ws;
    unsigned* ws_u = (unsigned*)ws;
    float* slots = ws_f + 576;
    float* S1    = ws_f + 1600;
    unsigned short* Db  = (unsigned short*)(ws + 4227072);
    unsigned short* Wb  = (unsigned short*)(ws + 6324224);
    unsigned short* x0b = (unsigned short*)(ws + 8421376);
    __shared__ float sp[256];
    __shared__ float s_small[16];

    if (blk < 256) {
        float lo0 = INFINITY, hi0 = -INFINITY, lo1 = INFINITY, hi1 = -INFINITY;
        int fbase = blk * 1024 + t;
#pragma unroll
        for (int q = 0; q < 4; q++) {
            int idx = fbase + q * 256;
            float4 a = ((const float4*)bdw)[idx];
            float4 b = ((const float4*)gdw)[idx];
            float4 w = ((const float4*)daw)[idx];
            lo0 = fminf(lo0, fminf(fminf(a.x, a.y), fminf(a.z, a.w)));
            hi0 = fmaxf(hi0, fmaxf(fmaxf(a.x, a.y), fmaxf(a.z, a.w)));
            lo1 = fminf(lo1, fminf(fminf(b.x, b.y), fminf(b.z, b.w)));
            hi1 = fmaxf(hi1, fmaxf(fmaxf(b.x, b.y), fmaxf(b.z, b.w)));
            ushort4 d, ww;
            d.x = f2bf(fabsf(a.x - b.x)); d.y = f2bf(fabsf(a.y - b.y));
            d.z = f2bf(fabsf(a.z - b.z)); d.w = f2bf(fabsf(a.w - b.w));
            ww.x = f2bf(w.x); ww.y = f2bf(w.y); ww.z = f2bf(w.z); ww.w = f2bf(w.w);
            ((ushort4*)Db)[idx] = d;
            ((ushort4*)Wb)[idx] = ww;
        }
        for (int off = 32; off; off >>= 1) {
            lo0 = fminf(lo0, __shfl_down(lo0, off));
            hi0 = fmaxf(hi0, __shfl_down(hi0, off));
            lo1 = fminf(lo1, __shfl_down(lo1, off));
            hi1 = fmaxf(hi1, __shfl_down(hi1, off));
        }
        if (lane == 0) { s_small[wid] = lo0; s_small[4 + wid] = hi0; s_small[8 + wid] = lo1; s_small[12 + wid] = hi1; }
        __syncthreads();
        if (t == 0) {
            slots[blk]       = fminf(fminf(s_small[0], s_small[1]), fminf(s_small[2], s_small[3]));
            slots[256 + blk] = fmaxf(fmaxf(s_small[4], s_small[5]), fmaxf(s_small[6], s_small[7]));
            slots[512 + blk] = fminf(fminf(s_small[8], s_small[9]), fminf(s_small[10], s_small[11]));
            slots[768 + blk] = fmaxf(fmaxf(s_small[12], s_small[13]), fmaxf(s_small[14], s_small[15]));
        }
    } else {
        const int blk2 = blk - 256;
        {   // S1 partial dots: 12 dots per block
            int d = t >> 4, kq = t & 15;
            if (d < 12) {
                int r = d >> 2, c = blk2 * 4 + (d & 3);
                const float4* bo4 = (const float4*)(bow + r * 1024);
                const float4* go4 = (const float4*)(gow + r * 1024);
                const float4* oa4 = (const float4*)(oaw + c * 1024);
                float s = 0.f;
#pragma unroll
                for (int k4 = kq * 16; k4 < kq * 16 + 16; ++k4) {
                    float4 bv = bo4[k4], gv = go4[k4], wv = oa4[k4];
                    s += fabsf(bv.x - gv.x) * wv.x + fabsf(bv.y - gv.y) * wv.y +
                         fabsf(bv.z - gv.z) * wv.z + fabsf(bv.w - gv.w) * wv.w;
                }
                sp[t] = s;
            }
            __syncthreads();
            if (t < 12) {
                float s = 0.f;
#pragma unroll
                for (int q = 0; q < 16; q++) s += sp[t * 16 + q];
                S1[(t >> 2) * 1024 + blk2 * 4 + (t & 3)] = s;
            }
        }
        if (blk == 256 || blk == 257) {  // bow/gow minmax
            const float* p = (blk == 256) ? bow : gow;
            float lo = INFINITY, hi = -INFINITY;
#pragma unroll
            for (int q = 0; q < 12; q++) { float v = p[q * 256 + t]; lo = fminf(lo, v); hi = fmaxf(hi, v); }
            for (int off = 32; off; off >>= 1) { lo = fminf(lo, __shfl_down(lo, off)); hi = fmaxf(hi, __shfl_down(hi, off)); }
            __syncthreads();
            if (lane == 0) { s_small[wid] = lo; s_small[4 + wid] = hi; }
            __syncthreads();
            if (t == 0) {
                ws_f[8 + 2 * (blk - 256)] = fminf(fminf(s_small[0], s_small[1]), fminf(s_small[2], s_small[3]));
                ws_f[9 + 2 * (blk - 256)] = fmaxf(fmaxf(s_small[4], s_small[5]), fmaxf(s_small[6], s_small[7]));
            }
        }
        if (blk == 258) {  // zero flags(512) + bins(40)
            ws_u[64 + t] = 0u;
            ws_u[320 + t] = 0u;
            if (t < 40) ws_u[16 + t] = 0u;
        }
        if (blk >= 260 && blk < 324) {  // x0b rows
            int row = blk - 260;
            float4 v = ((const float4*)(x + (size_t)row * 524288))[t];
            ushort4 o; o.x = f2bf(v.x); o.y = f2bf(v.y); o.z = f2bf(v.z); o.w = f2bf(v.w);
            ((ushort4*)x0b)[row * 256 + t] = o;
        }
    }
}

// =============================== K2 =========================================
__global__ __launch_bounds__(256) void k_main(
    const float* __restrict__ bdw, const float* __restrict__ gdw, const float* __restrict__ dab,
    const float* __restrict__ bow, const float* __restrict__ gow, const float* __restrict__ oab,
    char* __restrict__ ws) {
    const int blk = blockIdx.x, t = threadIdx.x;
    const int lane = t & 63, wid = t >> 6;
    const int lr = lane & 15, k8 = lane >> 4;
    const int wr = wid >> 1, wc = wid & 1;

    float* ws_f = (float*)ws;
    unsigned* ws_u = (unsigned*)ws;
    unsigned* bins  = ws_u + 16;
    unsigned* flags = ws_u + 64;
    float* slots = ws_f + 576;
    float* S1    = ws_f + 1600;
    float* pu1   = ws_f + 4736;
    float* part2 = ws_f + 8192;
    const unsigned short* Db  = (const unsigned short*)(ws + 4227072);
    const unsigned short* Wb  = (const unsigned short*)(ws + 6324224);
    const unsigned short* x0b = (const unsigned short*)(ws + 8421376);

    __shared__ short lds_a[2][2048];   // 32x64 bf16
    __shared__ short lds_b[2][4096];   // 64x64 bf16
    __shared__ short ldsT[32 * 72];
    __shared__ float s_small[16];
    __shared__ unsigned s_hist[NBINS];
    __shared__ float s_wg[2];

    // ---- histograms (exact f32 bin arithmetic) ----
    {
        int m, b0, nb;
        if (blk < 240)      { m = 0; b0 = blk;       nb = 240; }
        else if (blk < 480) { m = 1; b0 = blk - 240; nb = 240; }
        else if (blk < 496) { m = 2; b0 = blk - 480; nb = 16; }
        else                { m = 3; b0 = blk - 496; nb = 16; }
        const float* p = (m == 0) ? bdw : (m == 1) ? gdw : (m == 2) ? bow : gow;
        int n = (m < 2) ? 1048576 : 3072;
        float lo, hi;
        if (m < 2) {
            float l = slots[m * 512 + t];
            float h = slots[m * 512 + 256 + t];
            for (int off = 32; off; off >>= 1) { l = fminf(l, __shfl_down(l, off)); h = fmaxf(h, __shfl_down(h, off)); }
            if (lane == 0) { s_small[wid] = l; s_small[4 + wid] = h; }
            __syncthreads();
            lo = fminf(fminf(s_small[0], s_small[1]), fminf(s_small[2], s_small[3]));
            hi = fmaxf(fmaxf(s_small[4], s_small[5]), fmaxf(s_small[6], s_small[7]));
        } else {
            lo = ws_f[8 + 2 * (m - 2)];
            hi = ws_f[9 + 2 * (m - 2)];
        }
        float scale = __fdiv_rn(__fsub_rn(hi, lo), 10.0f);
        float lower[NBINS], upper[NBINS];
#pragma unroll
        for (int b = 0; b < NBINS; b++) {
            lower[b] = __fadd_rn(lo, __fmul_rn((float)b, scale));
            upper[b] = __fadd_rn(lower[b], scale);
        }
        unsigned cn[NBINS] = {};
#pragma unroll 4
        for (int i = b0 * 256 + t; i < n; i += nb * 256) {
            float v = p[i];
#pragma unroll
            for (int b = 0; b < NBINS; b++)
                if (v >= lower[b] && v < upper[b]) cn[b]++;
        }
        if (t < NBINS) s_hist[t] = 0;
        __syncthreads();
#pragma unroll
        for (int b = 0; b < NBINS; b++)
            if (cn[b]) atomicAdd(&s_hist[b], cn[b]);
        __syncthreads();
        if (t < NBINS && s_hist[t])
            __hip_atomic_fetch_add(&bins[m * NBINS + t], s_hist[t], __ATOMIC_RELAXED, __HIP_MEMORY_SCOPE_AGENT);
    }
    __syncthreads();
    if (t == 0) AST(&flags[blk], 1u);

    // ---- pu0 GEMM: 32x64 tile, BK=64, XCD-neighborhood swizzle ----
    // XCD c=blk&7 owns bi in [(c>>1)*8, +8) x bj in [(c&1)*8, +8):
    // A 8x64KB + B 8x128KB = 1.5MB -> L2-resident per XCD.
    const int c8 = blk & 7, rr = blk >> 3;
    const int bi = ((c8 >> 1) << 3) | (rr >> 3);   // 0..31
    const int bj = ((c8 & 1) << 3) | (rr & 7);     // 0..15
    f32x4 acc0 = {0.f, 0.f, 0.f, 0.f}, acc1 = {0.f, 0.f, 0.f, 0.f};
    {
        stage_slot(Db, lds_a[0], t, bi * 32, 0);
        stage_slot(Wb, lds_b[0], t, bj * 64, 0);
        stage_slot(Wb, lds_b[0], t + 256, bj * 64, 0);
        int cur = 0;
        for (int tt = 0; tt < 16; ++tt) {
            __syncthreads();  // all waves' gl2lds drained -> buffer cur ready
            if (tt + 1 < 16) {
                int k0 = (tt + 1) * 64;
                stage_slot(Db, lds_a[cur ^ 1], t, bi * 32, k0);
                stage_slot(Wb, lds_b[cur ^ 1], t, bj * 64, k0);
                stage_slot(Wb, lds_b[cur ^ 1], t + 256, bj * 64, k0);
            }
#pragma unroll
            for (int kk = 0; kk < 2; kk++) {
                bf8v a  = fr(lds_a[cur], wr * 16 + lr, kk * 4 + k8);
                bf8v b0 = fr(lds_b[cur], wc * 32 + lr, kk * 4 + k8);
                bf8v b1 = fr(lds_b[cur], wc * 32 + 16 + lr, kk * 4 + k8);
                acc0 = __builtin_amdgcn_mfma_f32_16x16x32_bf16(a, b0, acc0, 0, 0, 0);
                acc1 = __builtin_amdgcn_mfma_f32_16x16x32_bf16(a, b1, acc1, 0, 0, 0);
            }
            cur ^= 1;
        }
    }

    // ---- wait for histograms (done long ago), compute wg ----
    for (;;) {
        unsigned v0 = ALD(&flags[t]);
        unsigned v1 = ALD(&flags[t + 256]);
        if (__syncthreads_and((int)(v0 >= 1u && v1 >= 1u))) break;
        __builtin_amdgcn_s_sleep(1);
    }
    if (t == 0) {
        float e0 = ent_bins(&bins[0], 1048576.0f);
        float e1 = ent_bins(&bins[10], 1048576.0f);
        float e2 = ent_bins(&bins[20], 3072.0f);
        float e3 = ent_bins(&bins[30], 3072.0f);
        const float API = (float)(0.4 / M_PI);
        s_wg[0] = API * atanf(500.0f * (e0 - e1)) + 0.5f;
        s_wg[1] = API * atanf(500.0f * (e2 - e3)) + 0.5f;
    }
    __syncthreads();

    // ---- combine epilogue -> transposed bf16 tile in LDS ----
    {
        float wg = s_wg[0];
#pragma unroll
        for (int j = 0; j < 2; j++) {
            f32x4 a = j ? acc1 : acc0;
#pragma unroll
            for (int r = 0; r < 4; r++) {
                int il = wr * 16 + k8 * 4 + r;
                int jl = wc * 32 + j * 16 + lr;
                int ig = bi * 32 + il, jg = bj * 64 + jl;
                float s = a[r] + dab[jg];
                float wl = 1.0f / (1.0f + expf(-s));
                float w = wg * wl + (1.0f - wg);
                float o = bdw[ig * 1024 + jg] * w + gdw[ig * 1024 + jg] * (1.0f - w);
                ldsT[il * 72 + jl] = (short)f2bf(o);
            }
        }
        __syncthreads();
        // fused h-contribution: part2[bj][m 0..63][bi-panel c 0..31]
        f32x4 ah0 = {0.f, 0.f, 0.f, 0.f}, ah1 = {0.f, 0.f, 0.f, 0.f};
#pragma unroll
        for (int ks = 0; ks < 2; ks++) {
            int cl = wc * 16 + lr;
            bf8v b = *(const bf8v*)&ldsT[cl * 72 + ks * 32 + k8 * 8];
            bf8v a0 = *(const bf8v*)&x0b[(wr * 32 + lr) * 1024 + bj * 64 + ks * 32 + k8 * 8];
            bf8v a1 = *(const bf8v*)&x0b[(wr * 32 + 16 + lr) * 1024 + bj * 64 + ks * 32 + k8 * 8];
            ah0 = __builtin_amdgcn_mfma_f32_16x16x32_bf16(a0, b, ah0, 0, 0, 0);
            ah1 = __builtin_amdgcn_mfma_f32_16x16x32_bf16(a1, b, ah1, 0, 0, 0);
        }
#pragma unroll
        for (int mi = 0; mi < 2; mi++) {
            f32x4 ah = mi ? ah1 : ah0;
#pragma unroll
            for (int r = 0; r < 4; r++) {
                int m = wr * 32 + mi * 16 + k8 * 4 + r;
                int cg = bi * 32 + wc * 16 + lr;
                part2[((size_t)(bj * 64 + m) << 10) + cg] = ah[r];
            }
        }
    }
    if (blk < 16 && t < 192) {  // pu1 combine
        int r = t >> 6, c = blk * 64 + (t & 63);
        float s1 = S1[r * 1024 + c];
        float wl = 1.0f / (1.0f + expf(-(s1 + oab[c])));
        float wg = s_wg[1];
        float w = wg * wl + (1.0f - wg);
        pu1[r * 1024 + c] = bow[r * 1024 + c] * w + gow[r * 1024 + c] * (1.0f - w);
    }
}

// =============================== K3 =========================================
__global__ __launch_bounds__(256) void k_out(
    const float* __restrict__ bdb, const float* __restrict__ bob,
    float* __restrict__ out, const char* __restrict__ ws) {
    const int m = blockIdx.x, t = threadIdx.x;
    const int lane = t & 63, wid = t >> 6;
    const float* ws_f = (const float*)ws;
    const float* pu1   = ws_f + 4736;
    const float* part2 = ws_f + 8192;
    __shared__ float s_small[16];

    const int c0 = t * 4;
    f32x4 s = {0.f, 0.f, 0.f, 0.f};
#pragma unroll
    for (int b = 0; b < 16; b++)
        s += *(const f32x4*)(part2 + ((size_t)(b * 64 + m) << 10) + c0);
    float h0 = tanhf(s[0] + bdb[c0]);
    float h1 = tanhf(s[1] + bdb[c0 + 1]);
    float h2 = tanhf(s[2] + bdb[c0 + 2]);
    float h3 = tanhf(s[3] + bdb[c0 + 3]);
    float p0, p1, p2;
    {
        f32x4 q0 = *(const f32x4*)(pu1 + c0);
        f32x4 q1 = *(const f32x4*)(pu1 + 1024 + c0);
        f32x4 q2 = *(const f32x4*)(pu1 + 2048 + c0);
        p0 = h0 * q0[0] + h1 * q0[1] + h2 * q0[2] + h3 * q0[3];
        p1 = h0 * q1[0] + h1 * q1[1] + h2 * q1[2] + h3 * q1[3];
        p2 = h0 * q2[0] + h1 * q2[1] + h2 * q2[2] + h3 * q2[3];
    }
    for (int off = 32; off; off >>= 1) {
        p0 += __shfl_down(p0, off);
        p1 += __shfl_down(p1, off);
        p2 += __shfl_down(p2, off);
    }
    if (lane == 0) { s_small[wid] = p0; s_small[4 + wid] = p1; s_small[8 + wid] = p2; }
    __syncthreads();
    if (t == 0) {
        out[m * 3 + 0] = s_small[0] + s_small[1] + s_small[2] + s_small[3] + bob[0];
        out[m * 3 + 1] = s_small[4] + s_small[5] + s_small[6] + s_small[7] + bob[1];
        out[m * 3 + 2] = s_small[8] + s_small[9] + s_small[10] + s_small[11] + bob[2];
    }
}

extern "C" void kernel_launch(void* const* d_in, const int* in_sizes, int n_in,
                              void* d_out, int out_size, void* d_ws, size_t ws_size,
                              hipStream_t stream) {
    const float* x   = (const float*)d_in[0];
    const float* bdw = (const float*)d_in[1];
    const float* bdb = (const float*)d_in[2];
    const float* bow = (const float*)d_in[3];
    const float* bob = (const float*)d_in[4];
    const float* gdw = (const float*)d_in[5];
    const float* gow = (const float*)d_in[6];
    const float* daw = (const float*)d_in[7];
    const float* dab = (const float*)d_in[8];
    const float* oaw = (const float*)d_in[9];
    const float* oab = (const float*)d_in[10];
    float* out = (float*)d_out;
    char* ws = (char*)d_ws;

    k_prep<<<512, 256, 0, stream>>>(x, bdw, bow, gdw, gow, daw, oaw, ws);
    k_main<<<512, 256, 0, stream>>>(bdw, gdw, dab, bow, gow, oab, ws);
    k_out<<<64, 256, 0, stream>>>(bdb, bob, out, ws);
}